// Round 3
// baseline (1008.171 us; speedup 1.0000x reference)
//
#include <hip/hip_runtime.h>

typedef unsigned short u16;
typedef u16 u16x4 __attribute__((ext_vector_type(4)));
typedef u16 u16x8 __attribute__((ext_vector_type(8)));
typedef __bf16 bf16x8 __attribute__((ext_vector_type(8)));
typedef float f32x4 __attribute__((ext_vector_type(4)));

#define B_    2
#define L_    4096
#define H_    1024
#define INTER 2048
#define NSTATE 128
#define HEADS 32
#define P_    64
#define CHUNK 256
#define NC    16
#define CONVD 2304
#define PROJ  4384
#define PROJP 4480     // padded N for GEMM tiles (35 x 128)
#define XBCW  2432     // xBC f32 buffer width (PROJP - 2048)
#define MTOK  8192     // B_*L_

__device__ __forceinline__ u16 f2bf(float f) {
  unsigned u = __float_as_uint(f);
  u += 0x7fffu + ((u >> 16) & 1u);   // RNE
  return (u16)(u >> 16);
}
__device__ __forceinline__ float bf2f(u16 u) {
  return __uint_as_float(((unsigned)u) << 16);
}
__device__ __forceinline__ bf16x8 asbf(u16x8 v) {
  union { u16x8 u; bf16x8 b; } x; x.u = v; return x.b;
}

// ---------------- casts ----------------
__global__ void cast_bf16_k(const float* __restrict__ in, u16* __restrict__ out) {
  size_t i = ((size_t)blockIdx.x * 256 + threadIdx.x) * 4;
  float4 v = *(const float4*)(in + i);
  u16x4 o = { f2bf(v.x), f2bf(v.y), f2bf(v.z), f2bf(v.w) };
  *(u16x4*)(out + i) = o;
}

__global__ void cast_w1_k(const float* __restrict__ in, u16* __restrict__ out) {
  size_t i = ((size_t)blockIdx.x * 256 + threadIdx.x) * 4;
  u16x4 o = { 0, 0, 0, 0 };
  if (i < (size_t)PROJ * H_) {
    float4 v = *(const float4*)(in + i);
    o = (u16x4){ f2bf(v.x), f2bf(v.y), f2bf(v.z), f2bf(v.w) };
  }
  *(u16x4*)(out + i) = o;   // rows 4384..4479 zero-padded
}

// ---------------- bf16 MFMA GEMM: C[M,N] = A[M,K] * B[N,K]^T ----------------
// SPLIT=0: plain f32 C (ldc). SPLIT=1: cols<2048 -> bf16 gateb, else f32 xbcf.
template<int SPLIT>
__global__ __launch_bounds__(256) void gemm_bt_k(
    const u16* __restrict__ A, const u16* __restrict__ Bm, float* __restrict__ C,
    u16* __restrict__ gateb, float* __restrict__ xbcf,
    const int K, const int ldc) {
  __shared__ u16 Als[4096];
  __shared__ u16 Bls[4096];
  const int tid = threadIdx.x;
  const int bn = blockIdx.x, bm = blockIdx.y;
  const u16* Ab = A + (size_t)bm * 128 * K;
  const u16* Bb = Bm + (size_t)bn * 128 * K;
  const int row = tid >> 2, col = (tid & 3) << 3;
  const int lane = tid & 63;
  const int wr = ((tid >> 7) & 1) << 6;
  const int wc = ((tid >> 6) & 1) << 6;
  const int fr = lane & 15;
  const int fk = (lane >> 4) << 3;
  f32x4 acc[4][4] = {};
  const size_t rA0 = (size_t)row * K + col, rA1 = (size_t)(row + 64) * K + col;
  u16x8 ra0 = *(const u16x8*)(Ab + rA0);
  u16x8 ra1 = *(const u16x8*)(Ab + rA1);
  u16x8 rb0 = *(const u16x8*)(Bb + rA0);
  u16x8 rb1 = *(const u16x8*)(Bb + rA1);
  const int nk = K >> 5;
  for (int kt = 0; kt < nk; ++kt) {
    *(u16x8*)(Als + tid * 8) = ra0;
    *(u16x8*)(Als + 2048 + tid * 8) = ra1;
    *(u16x8*)(Bls + tid * 8) = rb0;
    *(u16x8*)(Bls + 2048 + tid * 8) = rb1;
    __syncthreads();
    if (kt + 1 < nk) {
      const size_t ko = (size_t)(kt + 1) * 32;
      ra0 = *(const u16x8*)(Ab + rA0 + ko);
      ra1 = *(const u16x8*)(Ab + rA1 + ko);
      rb0 = *(const u16x8*)(Bb + rA0 + ko);
      rb1 = *(const u16x8*)(Bb + rA1 + ko);
    }
    bf16x8 af[4], bfv[4];
#pragma unroll
    for (int m = 0; m < 4; ++m)
      af[m] = asbf(*(const u16x8*)(Als + (wr + m * 16 + fr) * 32 + fk));
#pragma unroll
    for (int n = 0; n < 4; ++n)
      bfv[n] = asbf(*(const u16x8*)(Bls + (wc + n * 16 + fr) * 32 + fk));
#pragma unroll
    for (int m = 0; m < 4; ++m)
#pragma unroll
      for (int n = 0; n < 4; ++n)
        acc[m][n] = __builtin_amdgcn_mfma_f32_16x16x32_bf16(af[m], bfv[n], acc[m][n], 0, 0, 0);
    __syncthreads();
  }
  const int crow = bm * 128 + wr + ((lane >> 4) << 2);
  if (SPLIT == 0) {
    float* Cp = C + (size_t)crow * ldc + bn * 128 + wc + fr;
#pragma unroll
    for (int m = 0; m < 4; ++m)
#pragma unroll
      for (int n = 0; n < 4; ++n)
#pragma unroll
        for (int j = 0; j < 4; ++j)
          Cp[(size_t)(m * 16 + j) * ldc + n * 16] = acc[m][n][j];
  } else if (bn < 16) {   // gate columns -> bf16
    u16* Gp = gateb + (size_t)crow * INTER + bn * 128 + wc + fr;
#pragma unroll
    for (int m = 0; m < 4; ++m)
#pragma unroll
      for (int n = 0; n < 4; ++n)
#pragma unroll
        for (int j = 0; j < 4; ++j)
          Gp[(size_t)(m * 16 + j) * INTER + n * 16] = f2bf(acc[m][n][j]);
  } else {                // xBC (+dt tail, unused) columns -> f32
    float* Xp = xbcf + (size_t)crow * XBCW + (bn - 16) * 128 + wc + fr;
#pragma unroll
    for (int m = 0; m < 4; ++m)
#pragma unroll
      for (int n = 0; n < 4; ++n)
#pragma unroll
        for (int j = 0; j < 4; ++j)
          Xp[(size_t)(m * 16 + j) * XBCW + n * 16] = acc[m][n][j];
  }
}

// ---------------- exact f32 dt columns + softplus ----------------
__global__ __launch_bounds__(256) void dtproj_k(
    const float* __restrict__ hs, const float* __restrict__ w1,
    const float* __restrict__ dt_bias, float* __restrict__ dtb) {
  __shared__ float hrow[H_];
  __shared__ float part[HEADS][8];
  const int m = blockIdx.x, t = threadIdx.x;
  *(float4*)(hrow + t * 4) = *(const float4*)(hs + (size_t)m * H_ + t * 4);
  __syncthreads();
  const int h = t & 31, pg = t >> 5;
  const float* wr = w1 + (size_t)(PROJ - HEADS + h) * H_ + pg * 128;
  const float* xr = hrow + pg * 128;
  float s = 0.f;
#pragma unroll 8
  for (int k = 0; k < 128; k += 4) {
    const float4 wv = *(const float4*)(wr + k);
    const float4 xv = *(const float4*)(xr + k);
    s += wv.x * xv.x + wv.y * xv.y + wv.z * xv.z + wv.w * xv.w;
  }
  part[h][pg] = s;
  __syncthreads();
  if (t < HEADS) {
    float z = dt_bias[t];
#pragma unroll
    for (int i = 0; i < 8; ++i) z += part[t][i];
    const float sp = z > 0.f ? z + log1pf(__expf(-z)) : log1pf(__expf(z));
    dtb[(size_t)m * HEADS + t] = sp;
  }
}

// ---------------- depthwise causal conv(K=4) + SiLU ----------------
__global__ __launch_bounds__(256) void conv_silu_k(
    const float* __restrict__ xbcf, const float* __restrict__ cw,
    const float* __restrict__ cbv,
    u16* __restrict__ xb16, float* __restrict__ Bbuf, float* __restrict__ Cbuf) {
  const int m = blockIdx.x;
  const int l = m & (L_ - 1);
  const int t = threadIdx.x;
  const float* pr = xbcf + (size_t)m * XBCW;
#pragma unroll
  for (int i = 0; i < 9; ++i) {
    const int ch = t + (i << 8);  // 0..2303
    float acc = cbv[ch];
    const float* w = cw + ch * 4;
#pragma unroll
    for (int k = 0; k < 4; ++k) {
      const int d = k - 3;
      if (l + d >= 0) acc += w[k] * pr[(long)d * XBCW + ch];
    }
    const float v = acc / (1.f + __expf(-acc));
    if (ch < INTER) xb16[(size_t)m * INTER + ch] = f2bf(v);
    else if (ch < INTER + NSTATE) Bbuf[(size_t)m * NSTATE + (ch - INTER)] = v;
    else Cbuf[(size_t)m * NSTATE + (ch - INTER - NSTATE)] = v;
  }
}

// ---------------- per-(b,c,h) dt chunk sums ----------------
__global__ void dtsum_k(const float* __restrict__ dtb, float* __restrict__ dts) {
  const int idx = blockIdx.x * 256 + threadIdx.x;  // (b*NC+c)*HEADS+h, 1024 total
  const int h = idx & 31, c = (idx >> 5) & 15, b = idx >> 9;
  const float* p = dtb + (size_t)(b * L_ + c * CHUNK) * HEADS + h;
  float s = 0.f;
  for (int i = 0; i < CHUNK; ++i) s += p[(size_t)i * HEADS];
  dts[idx] = s;
}

// ---------------- CB[l][s] = <C_l, B_s> per chunk (head-shared) ----------------
__global__ __launch_bounds__(256) void cb_k(
    const float* __restrict__ Bbuf, const float* __restrict__ Cbuf,
    float* __restrict__ CBb) {
  __shared__ float crow[NSTATE];
  const int bx = blockIdx.x;  // token index of row l
  const int t = threadIdx.x;
  if (t < NSTATE) crow[t] = Cbuf[(size_t)bx * NSTATE + t];
  __syncthreads();
  const int cbase = bx & ~(CHUNK - 1);
  const float* Brow = Bbuf + (size_t)(cbase + t) * NSTATE;
  float s = 0.f;
#pragma unroll 8
  for (int n = 0; n < NSTATE; n += 4) {
    const float4 bv = *(const float4*)(Brow + n);
    const float4 cv = *(const float4*)(crow + n);
    s += bv.x * cv.x + bv.y * cv.y + bv.z * cv.z + bv.w * cv.w;
  }
  CBb[(size_t)bx * CHUNK + t] = s;
}

// ---------------- Yd (intra-chunk) + chunk states, per (b,c,h) ----------------
__global__ __launch_bounds__(512) void yd_states_k(
    const u16* __restrict__ xb16, const float* __restrict__ Bbuf,
    const float* __restrict__ dtb, const float* __restrict__ CBb,
    const float* __restrict__ A_log, float* __restrict__ ybuf,
    float* __restrict__ states) {
  __shared__ u16 Xs[CHUNK * P_];       // X = x*dt, bf16
  __shared__ float acs[CHUNK];
  __shared__ float dec[CHUNK];
  const int bx = blockIdx.x;
  const int h = bx & 31, c = (bx >> 5) & 15, b = bx >> 9;
  const int t = threadIdx.x;
  const int m0 = b * L_ + c * CHUNK;
  const float Ah = -__expf(A_log[h]);
  if (t < CHUNK) acs[t] = dtb[(size_t)(m0 + t) * HEADS + h];
  __syncthreads();
  {  // stage X (reads raw dt from acs[])
    const int s = t >> 1, p0 = (t & 1) * 32;
    const float dtv = acs[s];
    const u16* xr = xb16 + (size_t)(m0 + s) * INTER + h * P_ + p0;
    u16* xd = Xs + s * P_ + p0;
#pragma unroll
    for (int i = 0; i < 32; i += 8) {
      const u16x8 v = *(const u16x8*)(xr + i);
      u16x8 o;
#pragma unroll
      for (int j = 0; j < 8; ++j) o[j] = f2bf(bf2f(v[j]) * dtv);
      *(u16x8*)(xd + i) = o;
    }
  }
  for (int off = 1; off < CHUNK; off <<= 1) {  // Hillis-Steele cumsum of dt
    float add = 0.f;
    if (t >= off && t < CHUNK) add = acs[t - off];
    __syncthreads();
    if (t >= off && t < CHUNK) acs[t] += add;
    __syncthreads();
  }
  {
    const float cum = (t < CHUNK) ? acs[t] : 0.f;
    const float tot = acs[CHUNK - 1];
    __syncthreads();
    if (t < CHUNK) {
      acs[t] = Ah * cum;                  // Acs (inclusive)
      dec[t] = __expf(Ah * (tot - cum));  // decay_states
    }
    __syncthreads();
  }
  {  // states[h][p][n] = sum_s B[s][n]*dec[s]*X[s][p]
    float sacc[16];
#pragma unroll
    for (int i = 0; i < 16; ++i) sacc[i] = 0.f;
    const int n = t & 127, pg = (t >> 7) << 4;
    const float* Bp = Bbuf + (size_t)m0 * NSTATE + n;
    for (int s = 0; s < CHUNK; ++s) {
      const float w = Bp[(size_t)s * NSTATE] * dec[s];
      const u16x8* xr = (const u16x8*)(Xs + s * P_ + pg);
      const u16x8 x0 = xr[0], x1 = xr[1];
#pragma unroll
      for (int i = 0; i < 8; ++i) {
        sacc[i]     += w * bf2f(x0[i]);
        sacc[8 + i] += w * bf2f(x1[i]);
      }
    }
    float* sp = states + ((size_t)((b * NC + c) * HEADS + h) * P_ + pg) * NSTATE + n;
#pragma unroll
    for (int i = 0; i < 16; ++i) sp[(size_t)i * NSTATE] = sacc[i];
  }
  {  // Yd[l][p] = sum_{s<=l} CB[l][s]*exp(Acs[l]-Acs[s])*X[s][p]
    float yacc[32];
#pragma unroll
    for (int i = 0; i < 32; ++i) yacc[i] = 0.f;
    const int l = t >> 1, ph = (t & 1) * 32;
    const float* cbr = CBb + (size_t)(m0 + l) * CHUNK;
    const float acl = acs[l];
    for (int s = 0; s <= l; ++s) {
      const float w = cbr[s] * __expf(acl - acs[s]);
      const u16x8* xr = (const u16x8*)(Xs + s * P_ + ph);
      const u16x8 x0 = xr[0], x1 = xr[1], x2 = xr[2], x3 = xr[3];
#pragma unroll
      for (int i = 0; i < 8; ++i) {
        yacc[i]      += w * bf2f(x0[i]);
        yacc[8 + i]  += w * bf2f(x1[i]);
        yacc[16 + i] += w * bf2f(x2[i]);
        yacc[24 + i] += w * bf2f(x3[i]);
      }
    }
    float* yp = ybuf + (size_t)(m0 + l) * XBCW + h * P_ + ph;
#pragma unroll
    for (int i = 0; i < 32; ++i) yp[i] = yacc[i];
  }
}

// ---------------- inter-chunk scan (in place: states -> prev) ----------------
__global__ void scan_k(float* __restrict__ states, const float* __restrict__ dts,
                       const float* __restrict__ A_log) {
  const int gid = blockIdx.x * 256 + threadIdx.x;  // over B_*HEADS*8192
  const int b = gid >> 18;
  const int h = (gid >> 13) & 31;
  const int pn = gid & 8191;
  const float Ah = -__expf(A_log[h]);
  float carry = 0.f;
  float* sp = states + (size_t)b * (NC * HEADS * P_ * NSTATE) + (size_t)h * (P_ * NSTATE) + pn;
  for (int c = 0; c < NC; ++c) {
    const float dcv = __expf(Ah * dts[(b * NC + c) * HEADS + h]);
    float* q = sp + (size_t)c * (HEADS * P_ * NSTATE);
    const float st = *q;
    *q = carry;               // prev (pre-update carry)
    carry = carry * dcv + st;
  }
}

// ---------------- Yo + D*x, finalize y ----------------
__global__ __launch_bounds__(512) void yo_final_k(
    const u16* __restrict__ xb16, const float* __restrict__ Cbuf,
    const float* __restrict__ dtb, const float* __restrict__ prev,
    const float* __restrict__ A_log, const float* __restrict__ Dv,
    float* __restrict__ ybuf) {
  __shared__ float Pv[P_ * NSTATE];
  __shared__ float acs[CHUNK];
  const int bx = blockIdx.x;
  const int h = bx & 31, c = (bx >> 5) & 15, b = bx >> 9;
  const int t = threadIdx.x;
  const int m0 = b * L_ + c * CHUNK;
  const float Ah = -__expf(A_log[h]);
  const float Dh = Dv[h];
  if (t < CHUNK) acs[t] = dtb[(size_t)(m0 + t) * HEADS + h];
  const float* pp = prev + (size_t)((b * NC + c) * HEADS + h) * (P_ * NSTATE);
#pragma unroll
  for (int i = 0; i < 16; ++i) Pv[t + i * 512] = pp[t + i * 512];
  __syncthreads();
  for (int off = 1; off < CHUNK; off <<= 1) {
    float add = 0.f;
    if (t >= off && t < CHUNK) add = acs[t - off];
    __syncthreads();
    if (t >= off && t < CHUNK) acs[t] += add;
    __syncthreads();
  }
  const int l = t >> 1, ph = (t & 1) * 32;
  const float el = __expf(Ah * acs[l]);
  float yacc[32];
#pragma unroll
  for (int i = 0; i < 32; ++i) yacc[i] = 0.f;
  const float* cr = Cbuf + (size_t)(m0 + l) * NSTATE;
  for (int n = 0; n < NSTATE; n += 4) {
    const float4 cv = *(const float4*)(cr + n);
#pragma unroll
    for (int i = 0; i < 32; ++i) {
      const float4 pv = *(const float4*)(Pv + (ph + i) * NSTATE + n);
      yacc[i] += cv.x * pv.x + cv.y * pv.y + cv.z * pv.z + cv.w * pv.w;
    }
  }
  float* yp = ybuf + (size_t)(m0 + l) * XBCW + h * P_ + ph;
  const u16* xp = xb16 + (size_t)(m0 + l) * INTER + h * P_ + ph;
  const u16x8* xv = (const u16x8*)xp;
#pragma unroll
  for (int q = 0; q < 4; ++q) {
    const u16x8 x8 = xv[q];
#pragma unroll
    for (int j = 0; j < 8; ++j)
      yp[q * 8 + j] += el * yacc[q * 8 + j] + Dh * bf2f(x8[j]);
  }
}

// ---------------- LayerNorm * SiLU(gate) -> bf16 ----------------
__global__ __launch_bounds__(256) void ln_gate_k(
    const float* __restrict__ ybuf, const u16* __restrict__ gateb,
    const float* __restrict__ lnw, const float* __restrict__ lnb,
    u16* __restrict__ yact) {
  __shared__ float red[8];
  const int m = blockIdx.x, t = threadIdx.x;
  const float* yr = ybuf + (size_t)m * XBCW;
  const float4 v0 = *(const float4*)(yr + t * 4);
  const float4 v1 = *(const float4*)(yr + 1024 + t * 4);
  float s = v0.x + v0.y + v0.z + v0.w + v1.x + v1.y + v1.z + v1.w;
  float ss = v0.x*v0.x + v0.y*v0.y + v0.z*v0.z + v0.w*v0.w
           + v1.x*v1.x + v1.y*v1.y + v1.z*v1.z + v1.w*v1.w;
#pragma unroll
  for (int off = 32; off > 0; off >>= 1) {
    s += __shfl_xor(s, off);
    ss += __shfl_xor(ss, off);
  }
  if ((t & 63) == 0) { red[(t >> 6) * 2] = s; red[(t >> 6) * 2 + 1] = ss; }
  __syncthreads();
  s = red[0] + red[2] + red[4] + red[6];
  ss = red[1] + red[3] + red[5] + red[7];
  const float mu = s * (1.f / INTER);
  const float rs = rsqrtf(ss * (1.f / INTER) - mu * mu + 1e-5f);
  const u16* gr = gateb + (size_t)m * INTER;
  const u16x4 g0 = *(const u16x4*)(gr + t * 4);
  const u16x4 g1 = *(const u16x4*)(gr + 1024 + t * 4);
  auto act = [&](float y, u16 gu, int idx) -> u16 {
    const float g = bf2f(gu);
    const float yn = (y - mu) * rs * lnw[idx] + lnb[idx];
    const float sg = g / (1.f + __expf(-g));
    return f2bf(yn * sg);
  };
  const int i0 = t * 4, i1 = 1024 + t * 4;
  u16x4 o0 = { act(v0.x, g0[0], i0), act(v0.y, g0[1], i0 + 1),
               act(v0.z, g0[2], i0 + 2), act(v0.w, g0[3], i0 + 3) };
  u16x4 o1 = { act(v1.x, g1[0], i1), act(v1.y, g1[1], i1 + 1),
               act(v1.z, g1[2], i1 + 2), act(v1.w, g1[3], i1 + 3) };
  *(u16x4*)(yact + (size_t)m * INTER + i0) = o0;
  *(u16x4*)(yact + (size_t)m * INTER + i1) = o1;
}

// ---------------- launch ----------------
extern "C" void kernel_launch(void* const* d_in, const int* in_sizes, int n_in,
                              void* d_out, int out_size, void* d_ws, size_t ws_size,
                              hipStream_t stream) {
  (void)in_sizes; (void)n_in; (void)out_size; (void)ws_size;
  const float* hs     = (const float*)d_in[0];
  const float* w1     = (const float*)d_in[1];
  const float* cw     = (const float*)d_in[2];
  const float* cbv    = (const float*)d_in[3];
  const float* dtbias = (const float*)d_in[4];
  const float* alog   = (const float*)d_in[5];
  const float* Dv     = (const float*)d_in[6];
  const float* lnw    = (const float*)d_in[7];
  const float* lnb    = (const float*)d_in[8];
  const float* w2     = (const float*)d_in[9];
  float* out = (float*)d_out;
  char* ws = (char*)d_ws;
  size_t off = 0;
  auto alloc = [&](size_t bytes) {
    void* p = ws + off; off += (bytes + 255) & ~(size_t)255; return p;
  };
  // total ~210 MiB
  u16*   hb     = (u16*)alloc((size_t)MTOK * H_ * 2);        // 16 MiB; CBb aliases after gemm1
  float* CBb    = (float*)hb;                                //  8 MiB alias
  u16*   w1b    = (u16*)alloc((size_t)PROJP * H_ * 2);       //  8.75 MiB
  u16*   w2b    = (u16*)alloc((size_t)H_ * INTER * 2);       //  4 MiB
  u16*   gateb  = (u16*)alloc((size_t)MTOK * INTER * 2);     // 32 MiB
  float* xbcf   = (float*)alloc((size_t)MTOK * XBCW * 4);    // 76 MiB; ybuf aliases after conv
  float* ybuf   = xbcf;
  u16*   xb16   = (u16*)alloc((size_t)MTOK * INTER * 2);     // 32 MiB; yact aliases after yo_final
  u16*   yact   = xb16;
  float* Bbuf   = (float*)alloc((size_t)MTOK * NSTATE * 4);  //  4 MiB
  float* Cbuf   = (float*)alloc((size_t)MTOK * NSTATE * 4);  //  4 MiB
  float* dtb    = (float*)alloc((size_t)MTOK * HEADS * 4);   //  1 MiB
  float* dts    = (float*)alloc(1024 * 4);
  float* states = (float*)alloc((size_t)B_ * NC * HEADS * P_ * NSTATE * 4);  // 32 MiB

  cast_bf16_k<<<MTOK * H_ / 1024, 256, 0, stream>>>(hs, hb);
  cast_w1_k<<<PROJP * H_ / 1024, 256, 0, stream>>>(w1, w1b);
  cast_bf16_k<<<H_ * INTER / 1024, 256, 0, stream>>>(w2, w2b);
  dtproj_k<<<MTOK, 256, 0, stream>>>(hs, w1, dtbias, dtb);
  gemm_bt_k<1><<<dim3(PROJP / 128, MTOK / 128), 256, 0, stream>>>(
      hb, w1b, nullptr, gateb, xbcf, H_, 0);
  conv_silu_k<<<MTOK, 256, 0, stream>>>(xbcf, cw, cbv, xb16, Bbuf, Cbuf);
  dtsum_k<<<4, 256, 0, stream>>>(dtb, dts);
  cb_k<<<MTOK, 256, 0, stream>>>(Bbuf, Cbuf, CBb);
  yd_states_k<<<B_ * NC * HEADS, 512, 0, stream>>>(xb16, Bbuf, dtb, CBb, alog, ybuf, states);
  scan_k<<<B_ * HEADS * P_ * NSTATE / 256, 256, 0, stream>>>(states, dts, alog);
  yo_final_k<<<B_ * NC * HEADS, 512, 0, stream>>>(xb16, Cbuf, dtb, states, alog, Dv, ybuf);
  ln_gate_k<<<MTOK, 256, 0, stream>>>(ybuf, gateb, lnw, lnb, yact);
  gemm_bt_k<0><<<dim3(H_ / 128, MTOK / 128), 256, 0, stream>>>(
      yact, w2b, out, nullptr, nullptr, INTER, H_);
}

// Round 5
// 803.225 us; speedup vs baseline: 1.2552x; 1.2552x over previous
//
#include <hip/hip_runtime.h>

typedef unsigned short u16;
typedef u16 u16x4 __attribute__((ext_vector_type(4)));
typedef u16 u16x8 __attribute__((ext_vector_type(8)));
typedef __bf16 bf16x8 __attribute__((ext_vector_type(8)));
typedef float f32x4 __attribute__((ext_vector_type(4)));

#define B_    2
#define L_    4096
#define H_    1024
#define INTER 2048
#define NSTATE 128
#define HEADS 32
#define P_    64
#define CHUNK 256
#define NC    16
#define CONVD 2304
#define PROJ  4384
#define PROJP 4480     // padded N for GEMM tiles (35 x 128)
#define XBCW  2432     // xBC f32 buffer width (PROJP - 2048)
#define MTOK  8192     // B_*L_

__device__ __forceinline__ u16 f2bf(float f) {
  unsigned u = __float_as_uint(f);
  u += 0x7fffu + ((u >> 16) & 1u);   // RNE
  return (u16)(u >> 16);
}
__device__ __forceinline__ float bf2f(u16 u) {
  return __uint_as_float(((unsigned)u) << 16);
}
__device__ __forceinline__ bf16x8 asbf(u16x8 v) {
  union { u16x8 u; bf16x8 b; } x; x.u = v; return x.b;
}

// ---------------- casts ----------------
__global__ void cast_bf16_k(const float* __restrict__ in, u16* __restrict__ out) {
  size_t i = ((size_t)blockIdx.x * 256 + threadIdx.x) * 4;
  float4 v = *(const float4*)(in + i);
  u16x4 o = { f2bf(v.x), f2bf(v.y), f2bf(v.z), f2bf(v.w) };
  *(u16x4*)(out + i) = o;
}

__global__ void cast_w1_k(const float* __restrict__ in, u16* __restrict__ out) {
  size_t i = ((size_t)blockIdx.x * 256 + threadIdx.x) * 4;
  u16x4 o = { 0, 0, 0, 0 };
  if (i < (size_t)PROJ * H_) {
    float4 v = *(const float4*)(in + i);
    o = (u16x4){ f2bf(v.x), f2bf(v.y), f2bf(v.z), f2bf(v.w) };
  }
  *(u16x4*)(out + i) = o;   // rows 4384..4479 zero-padded
}

// ---------------- bf16 MFMA GEMM: C[M,N] = A[M,K] * B[N,K]^T ----------------
// SPLIT=0: plain f32 C (ldc). SPLIT=1: cols<2048 -> bf16 gateb, else f32 xbcf.
template<int SPLIT>
__global__ __launch_bounds__(256) void gemm_bt_k(
    const u16* __restrict__ A, const u16* __restrict__ Bm, float* __restrict__ C,
    u16* __restrict__ gateb, float* __restrict__ xbcf,
    const int K, const int ldc) {
  __shared__ u16 Als[4096];
  __shared__ u16 Bls[4096];
  const int tid = threadIdx.x;
  const int bn = blockIdx.x, bm = blockIdx.y;
  const u16* Ab = A + (size_t)bm * 128 * K;
  const u16* Bb = Bm + (size_t)bn * 128 * K;
  const int row = tid >> 2, col = (tid & 3) << 3;
  const int lane = tid & 63;
  const int wr = ((tid >> 7) & 1) << 6;
  const int wc = ((tid >> 6) & 1) << 6;
  const int fr = lane & 15;
  const int fk = (lane >> 4) << 3;
  f32x4 acc[4][4] = {};
  const size_t rA0 = (size_t)row * K + col, rA1 = (size_t)(row + 64) * K + col;
  u16x8 ra0 = *(const u16x8*)(Ab + rA0);
  u16x8 ra1 = *(const u16x8*)(Ab + rA1);
  u16x8 rb0 = *(const u16x8*)(Bb + rA0);
  u16x8 rb1 = *(const u16x8*)(Bb + rA1);
  const int nk = K >> 5;
  for (int kt = 0; kt < nk; ++kt) {
    *(u16x8*)(Als + tid * 8) = ra0;
    *(u16x8*)(Als + 2048 + tid * 8) = ra1;
    *(u16x8*)(Bls + tid * 8) = rb0;
    *(u16x8*)(Bls + 2048 + tid * 8) = rb1;
    __syncthreads();
    if (kt + 1 < nk) {
      const size_t ko = (size_t)(kt + 1) * 32;
      ra0 = *(const u16x8*)(Ab + rA0 + ko);
      ra1 = *(const u16x8*)(Ab + rA1 + ko);
      rb0 = *(const u16x8*)(Bb + rA0 + ko);
      rb1 = *(const u16x8*)(Bb + rA1 + ko);
    }
    bf16x8 af[4], bfv[4];
#pragma unroll
    for (int m = 0; m < 4; ++m)
      af[m] = asbf(*(const u16x8*)(Als + (wr + m * 16 + fr) * 32 + fk));
#pragma unroll
    for (int n = 0; n < 4; ++n)
      bfv[n] = asbf(*(const u16x8*)(Bls + (wc + n * 16 + fr) * 32 + fk));
#pragma unroll
    for (int m = 0; m < 4; ++m)
#pragma unroll
      for (int n = 0; n < 4; ++n)
        acc[m][n] = __builtin_amdgcn_mfma_f32_16x16x32_bf16(af[m], bfv[n], acc[m][n], 0, 0, 0);
    __syncthreads();
  }
  const int crow = bm * 128 + wr + ((lane >> 4) << 2);
  if (SPLIT == 0) {
    float* Cp = C + (size_t)crow * ldc + bn * 128 + wc + fr;
#pragma unroll
    for (int m = 0; m < 4; ++m)
#pragma unroll
      for (int n = 0; n < 4; ++n)
#pragma unroll
        for (int j = 0; j < 4; ++j)
          Cp[(size_t)(m * 16 + j) * ldc + n * 16] = acc[m][n][j];
  } else if (bn < 16) {   // gate columns -> bf16
    u16* Gp = gateb + (size_t)crow * INTER + bn * 128 + wc + fr;
#pragma unroll
    for (int m = 0; m < 4; ++m)
#pragma unroll
      for (int n = 0; n < 4; ++n)
#pragma unroll
        for (int j = 0; j < 4; ++j)
          Gp[(size_t)(m * 16 + j) * INTER + n * 16] = f2bf(acc[m][n][j]);
  } else {                // xBC (+dt tail, unused) columns -> f32
    float* Xp = xbcf + (size_t)crow * XBCW + (bn - 16) * 128 + wc + fr;
#pragma unroll
    for (int m = 0; m < 4; ++m)
#pragma unroll
      for (int n = 0; n < 4; ++n)
#pragma unroll
        for (int j = 0; j < 4; ++j)
          Xp[(size_t)(m * 16 + j) * XBCW + n * 16] = acc[m][n][j];
  }
}

// ---------------- exact f32 dt columns + softplus ----------------
__global__ __launch_bounds__(256) void dtproj_k(
    const float* __restrict__ hs, const float* __restrict__ w1,
    const float* __restrict__ dt_bias, float* __restrict__ dtb) {
  __shared__ float hrow[H_];
  __shared__ float part[HEADS][8];
  const int m = blockIdx.x, t = threadIdx.x;
  *(float4*)(hrow + t * 4) = *(const float4*)(hs + (size_t)m * H_ + t * 4);
  __syncthreads();
  const int h = t & 31, pg = t >> 5;
  const float* wr = w1 + (size_t)(PROJ - HEADS + h) * H_ + pg * 128;
  const float* xr = hrow + pg * 128;
  float s = 0.f;
#pragma unroll 8
  for (int k = 0; k < 128; k += 4) {
    const float4 wv = *(const float4*)(wr + k);
    const float4 xv = *(const float4*)(xr + k);
    s += wv.x * xv.x + wv.y * xv.y + wv.z * xv.z + wv.w * xv.w;
  }
  part[h][pg] = s;
  __syncthreads();
  if (t < HEADS) {
    float z = dt_bias[t];
#pragma unroll
    for (int i = 0; i < 8; ++i) z += part[t][i];
    const float sp = z > 0.f ? z + log1pf(__expf(-z)) : log1pf(__expf(z));
    dtb[(size_t)m * HEADS + t] = sp;
  }
}

// ---------------- depthwise causal conv(K=4) + SiLU ----------------
__global__ __launch_bounds__(256) void conv_silu_k(
    const float* __restrict__ xbcf, const float* __restrict__ cw,
    const float* __restrict__ cbv,
    u16* __restrict__ xb16, float* __restrict__ Bbuf, float* __restrict__ Cbuf) {
  const int m = blockIdx.x;
  const int l = m & (L_ - 1);
  const int t = threadIdx.x;
  const float* pr = xbcf + (size_t)m * XBCW;
#pragma unroll
  for (int i = 0; i < 9; ++i) {
    const int ch = t + (i << 8);  // 0..2303
    float acc = cbv[ch];
    const float* w = cw + ch * 4;
#pragma unroll
    for (int k = 0; k < 4; ++k) {
      const int d = k - 3;
      if (l + d >= 0) acc += w[k] * pr[(long)d * XBCW + ch];
    }
    const float v = acc / (1.f + __expf(-acc));
    if (ch < INTER) xb16[(size_t)m * INTER + ch] = f2bf(v);
    else if (ch < INTER + NSTATE) Bbuf[(size_t)m * NSTATE + (ch - INTER)] = v;
    else Cbuf[(size_t)m * NSTATE + (ch - INTER - NSTATE)] = v;
  }
}

// ---------------- per-(b,c,h) dt chunk sums ----------------
__global__ void dtsum_k(const float* __restrict__ dtb, float* __restrict__ dts) {
  const int idx = blockIdx.x * 256 + threadIdx.x;  // (b*NC+c)*HEADS+h, 1024 total
  const int h = idx & 31, c = (idx >> 5) & 15, b = idx >> 9;
  const float* p = dtb + (size_t)(b * L_ + c * CHUNK) * HEADS + h;
  float s = 0.f;
  for (int i = 0; i < CHUNK; ++i) s += p[(size_t)i * HEADS];
  dts[idx] = s;
}

// ---------------- CB[l][s] = <C_l, B_s> per chunk (head-shared) ----------------
__global__ __launch_bounds__(256) void cb_k(
    const float* __restrict__ Bbuf, const float* __restrict__ Cbuf,
    float* __restrict__ CBb) {
  __shared__ float crow[NSTATE];
  const int bx = blockIdx.x;  // token index of row l
  const int t = threadIdx.x;
  if (t < NSTATE) crow[t] = Cbuf[(size_t)bx * NSTATE + t];
  __syncthreads();
  const int cbase = bx & ~(CHUNK - 1);
  const float* Brow = Bbuf + (size_t)(cbase + t) * NSTATE;
  float s = 0.f;
#pragma unroll 8
  for (int n = 0; n < NSTATE; n += 4) {
    const float4 bv = *(const float4*)(Brow + n);
    const float4 cv = *(const float4*)(crow + n);
    s += bv.x * cv.x + bv.y * cv.y + bv.z * cv.z + bv.w * cv.w;
  }
  CBb[(size_t)bx * CHUNK + t] = s;
}

// ---------------- Yd (intra-chunk) + chunk states via MFMA, per (b,c,h) ------
// LDS: acs[256] f32, dec[256] f32, Xt[64][256] bf16 transposed+swizzled.
// Yd[l][p]    = sum_{s<=l} (CB[l][s] * exp(acs_l - acs_s)) * X[s][p]
//             = MFMA(A=W on-the-fly, B=Xt)
// states[p][n]= sum_s X[s][p] * (B[s][n] * dec_s) = MFMA(A=Xt, B=Bw on-the-fly)
__global__ __launch_bounds__(512) void yd_states_k(
    const u16* __restrict__ xb16, const float* __restrict__ Bbuf,
    const float* __restrict__ dtb, const float* __restrict__ CBb,
    const float* __restrict__ A_log, float* __restrict__ ybuf,
    float* __restrict__ states) {
  __shared__ float acs[CHUNK];
  __shared__ float dec[CHUNK];
  __shared__ u16 Xt[P_ * CHUNK];     // [p][s] bf16, elem ^= (p&7)<<3
  const int bx = blockIdx.x;
  const int h = bx & 31, c = (bx >> 5) & 15, b = bx >> 9;
  const int t = threadIdx.x;
  const int m0 = b * L_ + c * CHUNK;
  const float Ah = -__expf(A_log[h]);
  if (t < CHUNK) acs[t] = dtb[(size_t)(m0 + t) * HEADS + h];
  __syncthreads();
  {  // stage Xt = (x*dt)^T, bf16, swizzled; reads raw dt from acs[]
#pragma unroll
    for (int i = 0; i < 4; ++i) {
      const int s = i * 64 + (t >> 3);
      const int p0 = (t & 7) * 8;
      const float dtv = acs[s];
      const u16x8 v = *(const u16x8*)(xb16 + (size_t)(m0 + s) * INTER + h * P_ + p0);
#pragma unroll
      for (int j = 0; j < 8; ++j)
        Xt[((p0 + j) * CHUNK + s) ^ (j << 3)] = f2bf(bf2f(v[j]) * dtv);
    }
  }
  for (int off = 1; off < CHUNK; off <<= 1) {  // Hillis-Steele cumsum of dt
    float add = 0.f;
    if (t >= off && t < CHUNK) add = acs[t - off];
    __syncthreads();
    if (t >= off && t < CHUNK) acs[t] += add;
    __syncthreads();
  }
  {
    const float cum = (t < CHUNK) ? acs[t] : 0.f;
    const float tot = acs[CHUNK - 1];
    __syncthreads();
    if (t < CHUNK) {
      acs[t] = Ah * cum;                  // Acs (inclusive)
      dec[t] = __expf(Ah * (tot - cum));  // decay_states
    }
    __syncthreads();
  }
  const int lane = t & 63;
  const int wv = t >> 6;        // wave id 0..7
  const int fr = lane & 15;     // row/col within 16-tile
  const int fu = lane >> 4;     // k-subgroup 0..3
  {  // ---- states: n-tile = wv; D[p][n] over 4 p-tiles ----
    f32x4 acc_st[4] = {};
    const float* Bg = Bbuf + (size_t)m0 * NSTATE + wv * 16 + fr;
#pragma unroll 2
    for (int ks = 0; ks < 8; ++ks) {
      const int s0 = ks * 32 + fu * 8;
      u16x8 bw;
#pragma unroll
      for (int j = 0; j < 8; ++j)
        bw[j] = f2bf(Bg[(size_t)(s0 + j) * NSTATE] * dec[s0 + j]);
#pragma unroll
      for (int pt = 0; pt < 4; ++pt) {
        const int p = pt * 16 + fr;
        const u16x8 xa = *(const u16x8*)(Xt + ((p * CHUNK + s0) ^ ((p & 7) << 3)));
        acc_st[pt] = __builtin_amdgcn_mfma_f32_16x16x32_bf16(asbf(xa), asbf(bw), acc_st[pt], 0, 0, 0);
      }
    }
    float* sp = states + (size_t)((b * NC + c) * HEADS + h) * (P_ * NSTATE);
#pragma unroll
    for (int pt = 0; pt < 4; ++pt)
#pragma unroll
      for (int reg = 0; reg < 4; ++reg)
        sp[(size_t)(pt * 16 + fu * 4 + reg) * NSTATE + wv * 16 + fr] = acc_st[pt][reg];
  }
  {  // ---- Yd: l-tiles {wv, 15-wv} (balanced triangular work) ----
#pragma unroll
    for (int rep = 0; rep < 2; ++rep) {
      const int lt = rep ? (15 - wv) : wv;
      const int l = lt * 16 + fr;
      const float acl = acs[l];
      const float* cbr = CBb + (size_t)(m0 + l) * CHUNK;
      f32x4 acc_yd[4] = {};
      const int ksn = (lt >> 1) + 1;
      for (int ks = 0; ks < ksn; ++ks) {
        const int s0 = ks * 32 + fu * 8;
        const float4 cb0 = *(const float4*)(cbr + s0);
        const float4 cb1 = *(const float4*)(cbr + s0 + 4);
        u16x8 w8;
#pragma unroll
        for (int j = 0; j < 8; ++j) {
          const int s = s0 + j;
          const float cb = j < 4 ? ((const float*)&cb0)[j] : ((const float*)&cb1)[j - 4];
          const float w = (s <= l) ? cb * __expf(acl - acs[s]) : 0.f;
          w8[j] = f2bf(w);
        }
#pragma unroll
        for (int pt = 0; pt < 4; ++pt) {
          const int p = pt * 16 + fr;
          const u16x8 xb = *(const u16x8*)(Xt + ((p * CHUNK + s0) ^ ((p & 7) << 3)));
          acc_yd[pt] = __builtin_amdgcn_mfma_f32_16x16x32_bf16(asbf(w8), asbf(xb), acc_yd[pt], 0, 0, 0);
        }
      }
#pragma unroll
      for (int pt = 0; pt < 4; ++pt)
#pragma unroll
        for (int reg = 0; reg < 4; ++reg)
          ybuf[(size_t)(m0 + lt * 16 + fu * 4 + reg) * XBCW + h * P_ + pt * 16 + fr] =
              acc_yd[pt][reg];
    }
  }
}

// ---------------- inter-chunk scan (in place: states -> prev) ----------------
__global__ void scan_k(float* __restrict__ states, const float* __restrict__ dts,
                       const float* __restrict__ A_log) {
  const int gid = blockIdx.x * 256 + threadIdx.x;  // over B_*HEADS*8192
  const int b = gid >> 18;
  const int h = (gid >> 13) & 31;
  const int pn = gid & 8191;
  const float Ah = -__expf(A_log[h]);
  float carry = 0.f;
  float* sp = states + (size_t)b * (NC * HEADS * P_ * NSTATE) + (size_t)h * (P_ * NSTATE) + pn;
  for (int c = 0; c < NC; ++c) {
    const float dcv = __expf(Ah * dts[(b * NC + c) * HEADS + h]);
    float* q = sp + (size_t)c * (HEADS * P_ * NSTATE);
    const float st = *q;
    *q = carry;               // prev (pre-update carry)
    carry = carry * dcv + st;
  }
}

// ---------------- Yo + D*x, finalize y ----------------
__global__ __launch_bounds__(512) void yo_final_k(
    const u16* __restrict__ xb16, const float* __restrict__ Cbuf,
    const float* __restrict__ dtb, const float* __restrict__ prev,
    const float* __restrict__ A_log, const float* __restrict__ Dv,
    float* __restrict__ ybuf) {
  __shared__ float Pv[P_ * NSTATE];
  __shared__ float acs[CHUNK];
  const int bx = blockIdx.x;
  const int h = bx & 31, c = (bx >> 5) & 15, b = bx >> 9;
  const int t = threadIdx.x;
  const int m0 = b * L_ + c * CHUNK;
  const float Ah = -__expf(A_log[h]);
  const float Dh = Dv[h];
  if (t < CHUNK) acs[t] = dtb[(size_t)(m0 + t) * HEADS + h];
  const float* pp = prev + (size_t)((b * NC + c) * HEADS + h) * (P_ * NSTATE);
#pragma unroll
  for (int i = 0; i < 16; ++i) Pv[t + i * 512] = pp[t + i * 512];
  __syncthreads();
  for (int off = 1; off < CHUNK; off <<= 1) {
    float add = 0.f;
    if (t >= off && t < CHUNK) add = acs[t - off];
    __syncthreads();
    if (t >= off && t < CHUNK) acs[t] += add;
    __syncthreads();
  }
  const int l = t >> 1, ph = (t & 1) * 32;
  const float el = __expf(Ah * acs[l]);
  float yacc[32];
#pragma unroll
  for (int i = 0; i < 32; ++i) yacc[i] = 0.f;
  const float* cr = Cbuf + (size_t)(m0 + l) * NSTATE;
  for (int n = 0; n < NSTATE; n += 4) {
    const float4 cv = *(const float4*)(cr + n);
#pragma unroll
    for (int i = 0; i < 32; ++i) {
      const float4 pv = *(const float4*)(Pv + (ph + i) * NSTATE + n);
      yacc[i] += cv.x * pv.x + cv.y * pv.y + cv.z * pv.z + cv.w * pv.w;
    }
  }
  float* yp = ybuf + (size_t)(m0 + l) * XBCW + h * P_ + ph;
  const u16* xp = xb16 + (size_t)(m0 + l) * INTER + h * P_ + ph;
  const u16x8* xv = (const u16x8*)xp;
#pragma unroll
  for (int q = 0; q < 4; ++q) {
    const u16x8 x8 = xv[q];
#pragma unroll
    for (int j = 0; j < 8; ++j)
      yp[q * 8 + j] += el * yacc[q * 8 + j] + Dh * bf2f(x8[j]);
  }
}

// ---------------- LayerNorm * SiLU(gate) -> bf16 ----------------
__global__ __launch_bounds__(256) void ln_gate_k(
    const float* __restrict__ ybuf, const u16* __restrict__ gateb,
    const float* __restrict__ lnw, const float* __restrict__ lnb,
    u16* __restrict__ yact) {
  __shared__ float red[8];
  const int m = blockIdx.x, t = threadIdx.x;
  const float* yr = ybuf + (size_t)m * XBCW;
  const float4 v0 = *(const float4*)(yr + t * 4);
  const float4 v1 = *(const float4*)(yr + 1024 + t * 4);
  float s = v0.x + v0.y + v0.z + v0.w + v1.x + v1.y + v1.z + v1.w;
  float ss = v0.x*v0.x + v0.y*v0.y + v0.z*v0.z + v0.w*v0.w
           + v1.x*v1.x + v1.y*v1.y + v1.z*v1.z + v1.w*v1.w;
#pragma unroll
  for (int off = 32; off > 0; off >>= 1) {
    s += __shfl_xor(s, off);
    ss += __shfl_xor(ss, off);
  }
  if ((t & 63) == 0) { red[(t >> 6) * 2] = s; red[(t >> 6) * 2 + 1] = ss; }
  __syncthreads();
  s = red[0] + red[2] + red[4] + red[6];
  ss = red[1] + red[3] + red[5] + red[7];
  const float mu = s * (1.f / INTER);
  const float rs = rsqrtf(ss * (1.f / INTER) - mu * mu + 1e-5f);
  const u16* gr = gateb + (size_t)m * INTER;
  const u16x4 g0 = *(const u16x4*)(gr + t * 4);
  const u16x4 g1 = *(const u16x4*)(gr + 1024 + t * 4);
  auto act = [&](float y, u16 gu, int idx) -> u16 {
    const float g = bf2f(gu);
    const float yn = (y - mu) * rs * lnw[idx] + lnb[idx];
    const float sg = g / (1.f + __expf(-g));
    return f2bf(yn * sg);
  };
  const int i0 = t * 4, i1 = 1024 + t * 4;
  u16x4 o0 = { act(v0.x, g0[0], i0), act(v0.y, g0[1], i0 + 1),
               act(v0.z, g0[2], i0 + 2), act(v0.w, g0[3], i0 + 3) };
  u16x4 o1 = { act(v1.x, g1[0], i1), act(v1.y, g1[1], i1 + 1),
               act(v1.z, g1[2], i1 + 2), act(v1.w, g1[3], i1 + 3) };
  *(u16x4*)(yact + (size_t)m * INTER + i0) = o0;
  *(u16x4*)(yact + (size_t)m * INTER + i1) = o1;
}

// ---------------- launch ----------------
extern "C" void kernel_launch(void* const* d_in, const int* in_sizes, int n_in,
                              void* d_out, int out_size, void* d_ws, size_t ws_size,
                              hipStream_t stream) {
  (void)in_sizes; (void)n_in; (void)out_size; (void)ws_size;
  const float* hs     = (const float*)d_in[0];
  const float* w1     = (const float*)d_in[1];
  const float* cw     = (const float*)d_in[2];
  const float* cbv    = (const float*)d_in[3];
  const float* dtbias = (const float*)d_in[4];
  const float* alog   = (const float*)d_in[5];
  const float* Dv     = (const float*)d_in[6];
  const float* lnw    = (const float*)d_in[7];
  const float* lnb    = (const float*)d_in[8];
  const float* w2     = (const float*)d_in[9];
  float* out = (float*)d_out;
  char* ws = (char*)d_ws;
  size_t off = 0;
  auto alloc = [&](size_t bytes) {
    void* p = ws + off; off += (bytes + 255) & ~(size_t)255; return p;
  };
  // total ~210 MiB
  u16*   hb     = (u16*)alloc((size_t)MTOK * H_ * 2);        // 16 MiB; CBb aliases after gemm1
  float* CBb    = (float*)hb;                                //  8 MiB alias
  u16*   w1b    = (u16*)alloc((size_t)PROJP * H_ * 2);       //  8.75 MiB
  u16*   w2b    = (u16*)alloc((size_t)H_ * INTER * 2);       //  4 MiB
  u16*   gateb  = (u16*)alloc((size_t)MTOK * INTER * 2);     // 32 MiB
  float* xbcf   = (float*)alloc((size_t)MTOK * XBCW * 4);    // 76 MiB; ybuf aliases after conv
  float* ybuf   = xbcf;
  u16*   xb16   = (u16*)alloc((size_t)MTOK * INTER * 2);     // 32 MiB; yact aliases after yo_final
  u16*   yact   = xb16;
  float* Bbuf   = (float*)alloc((size_t)MTOK * NSTATE * 4);  //  4 MiB
  float* Cbuf   = (float*)alloc((size_t)MTOK * NSTATE * 4);  //  4 MiB
  float* dtb    = (float*)alloc((size_t)MTOK * HEADS * 4);   //  1 MiB
  float* dts    = (float*)alloc(1024 * 4);
  float* states = (float*)alloc((size_t)B_ * NC * HEADS * P_ * NSTATE * 4);  // 32 MiB

  cast_bf16_k<<<MTOK * H_ / 1024, 256, 0, stream>>>(hs, hb);
  cast_w1_k<<<PROJP * H_ / 1024, 256, 0, stream>>>(w1, w1b);
  cast_bf16_k<<<H_ * INTER / 1024, 256, 0, stream>>>(w2, w2b);
  dtproj_k<<<MTOK, 256, 0, stream>>>(hs, w1, dtbias, dtb);
  gemm_bt_k<1><<<dim3(PROJP / 128, MTOK / 128), 256, 0, stream>>>(
      hb, w1b, nullptr, gateb, xbcf, H_, 0);
  conv_silu_k<<<MTOK, 256, 0, stream>>>(xbcf, cw, cbv, xb16, Bbuf, Cbuf);
  dtsum_k<<<4, 256, 0, stream>>>(dtb, dts);
  cb_k<<<MTOK, 256, 0, stream>>>(Bbuf, Cbuf, CBb);
  yd_states_k<<<B_ * NC * HEADS, 512, 0, stream>>>(xb16, Bbuf, dtb, CBb, alog, ybuf, states);
  scan_k<<<B_ * HEADS * P_ * NSTATE / 256, 256, 0, stream>>>(states, dts, alog);
  yo_final_k<<<B_ * NC * HEADS, 512, 0, stream>>>(xb16, Cbuf, dtb, states, alog, Dv, ybuf);
  ln_gate_k<<<MTOK, 256, 0, stream>>>(ybuf, gateb, lnw, lnb, yact);
  gemm_bt_k<0><<<dim3(H_ / 128, MTOK / 128), 256, 0, stream>>>(
      yact, w2b, out, nullptr, nullptr, INTER, H_);
}

// Round 6
// 693.609 us; speedup vs baseline: 1.4535x; 1.1580x over previous
//
#include <hip/hip_runtime.h>

typedef unsigned short u16;
typedef u16 u16x4 __attribute__((ext_vector_type(4)));
typedef u16 u16x8 __attribute__((ext_vector_type(8)));
typedef __bf16 bf16x8 __attribute__((ext_vector_type(8)));
typedef float f32x4 __attribute__((ext_vector_type(4)));

#define B_    2
#define L_    4096
#define H_    1024
#define INTER 2048
#define NSTATE 128
#define HEADS 32
#define P_    64
#define CHUNK 256
#define NC    16
#define CONVD 2304
#define PROJ  4384
#define PROJP 4480     // padded N for GEMM tiles (35 x 128)
#define XBCW  2432     // xBC f32 buffer width (PROJP - 2048)
#define MTOK  8192     // B_*L_

__device__ __forceinline__ u16 f2bf(float f) {
  unsigned u = __float_as_uint(f);
  u += 0x7fffu + ((u >> 16) & 1u);   // RNE
  return (u16)(u >> 16);
}
__device__ __forceinline__ float bf2f(u16 u) {
  return __uint_as_float(((unsigned)u) << 16);
}
__device__ __forceinline__ bf16x8 asbf(u16x8 v) {
  union { u16x8 u; bf16x8 b; } x; x.u = v; return x.b;
}

// ---------------- casts ----------------
__global__ void cast_bf16_k(const float* __restrict__ in, u16* __restrict__ out) {
  size_t i = ((size_t)blockIdx.x * 256 + threadIdx.x) * 4;
  float4 v = *(const float4*)(in + i);
  u16x4 o = { f2bf(v.x), f2bf(v.y), f2bf(v.z), f2bf(v.w) };
  *(u16x4*)(out + i) = o;
}

__global__ void cast_w1_k(const float* __restrict__ in, u16* __restrict__ out) {
  size_t i = ((size_t)blockIdx.x * 256 + threadIdx.x) * 4;
  u16x4 o = { 0, 0, 0, 0 };
  if (i < (size_t)PROJ * H_) {
    float4 v = *(const float4*)(in + i);
    o = (u16x4){ f2bf(v.x), f2bf(v.y), f2bf(v.z), f2bf(v.w) };
  }
  *(u16x4*)(out + i) = o;   // rows 4384..4479 zero-padded
}

// ---------------- bf16 MFMA GEMM: C[M,N] = A[M,K] * B[N,K]^T ----------------
// SPLIT=0: plain f32 C (ldc). SPLIT=1: cols<2048 -> bf16 gateb, else f32 xbcf.
template<int SPLIT>
__global__ __launch_bounds__(256) void gemm_bt_k(
    const u16* __restrict__ A, const u16* __restrict__ Bm, float* __restrict__ C,
    u16* __restrict__ gateb, float* __restrict__ xbcf,
    const int K, const int ldc) {
  __shared__ u16 Als[4096];
  __shared__ u16 Bls[4096];
  const int tid = threadIdx.x;
  const int bn = blockIdx.x, bm = blockIdx.y;
  const u16* Ab = A + (size_t)bm * 128 * K;
  const u16* Bb = Bm + (size_t)bn * 128 * K;
  const int row = tid >> 2, col = (tid & 3) << 3;
  const int lane = tid & 63;
  const int wr = ((tid >> 7) & 1) << 6;
  const int wc = ((tid >> 6) & 1) << 6;
  const int fr = lane & 15;
  const int fk = (lane >> 4) << 3;
  f32x4 acc[4][4] = {};
  const size_t rA0 = (size_t)row * K + col, rA1 = (size_t)(row + 64) * K + col;
  u16x8 ra0 = *(const u16x8*)(Ab + rA0);
  u16x8 ra1 = *(const u16x8*)(Ab + rA1);
  u16x8 rb0 = *(const u16x8*)(Bb + rA0);
  u16x8 rb1 = *(const u16x8*)(Bb + rA1);
  const int nk = K >> 5;
  for (int kt = 0; kt < nk; ++kt) {
    *(u16x8*)(Als + tid * 8) = ra0;
    *(u16x8*)(Als + 2048 + tid * 8) = ra1;
    *(u16x8*)(Bls + tid * 8) = rb0;
    *(u16x8*)(Bls + 2048 + tid * 8) = rb1;
    __syncthreads();
    if (kt + 1 < nk) {
      const size_t ko = (size_t)(kt + 1) * 32;
      ra0 = *(const u16x8*)(Ab + rA0 + ko);
      ra1 = *(const u16x8*)(Ab + rA1 + ko);
      rb0 = *(const u16x8*)(Bb + rA0 + ko);
      rb1 = *(const u16x8*)(Bb + rA1 + ko);
    }
    bf16x8 af[4], bfv[4];
#pragma unroll
    for (int m = 0; m < 4; ++m)
      af[m] = asbf(*(const u16x8*)(Als + (wr + m * 16 + fr) * 32 + fk));
#pragma unroll
    for (int n = 0; n < 4; ++n)
      bfv[n] = asbf(*(const u16x8*)(Bls + (wc + n * 16 + fr) * 32 + fk));
#pragma unroll
    for (int m = 0; m < 4; ++m)
#pragma unroll
      for (int n = 0; n < 4; ++n)
        acc[m][n] = __builtin_amdgcn_mfma_f32_16x16x32_bf16(af[m], bfv[n], acc[m][n], 0, 0, 0);
    __syncthreads();
  }
  const int crow = bm * 128 + wr + ((lane >> 4) << 2);
  if (SPLIT == 0) {
    float* Cp = C + (size_t)crow * ldc + bn * 128 + wc + fr;
#pragma unroll
    for (int m = 0; m < 4; ++m)
#pragma unroll
      for (int n = 0; n < 4; ++n)
#pragma unroll
        for (int j = 0; j < 4; ++j)
          Cp[(size_t)(m * 16 + j) * ldc + n * 16] = acc[m][n][j];
  } else if (bn < 16) {   // gate columns -> bf16
    u16* Gp = gateb + (size_t)crow * INTER + bn * 128 + wc + fr;
#pragma unroll
    for (int m = 0; m < 4; ++m)
#pragma unroll
      for (int n = 0; n < 4; ++n)
#pragma unroll
        for (int j = 0; j < 4; ++j)
          Gp[(size_t)(m * 16 + j) * INTER + n * 16] = f2bf(acc[m][n][j]);
  } else {                // xBC (+dt tail, unused) columns -> f32
    float* Xp = xbcf + (size_t)crow * XBCW + (bn - 16) * 128 + wc + fr;
#pragma unroll
    for (int m = 0; m < 4; ++m)
#pragma unroll
      for (int n = 0; n < 4; ++n)
#pragma unroll
        for (int j = 0; j < 4; ++j)
          Xp[(size_t)(m * 16 + j) * XBCW + n * 16] = acc[m][n][j];
  }
}

// ---------------- exact f32 dt columns + softplus ----------------
__global__ __launch_bounds__(256) void dtproj_k(
    const float* __restrict__ hs, const float* __restrict__ w1,
    const float* __restrict__ dt_bias, float* __restrict__ dtb) {
  __shared__ float hrow[H_];
  __shared__ float part[HEADS][8];
  const int m = blockIdx.x, t = threadIdx.x;
  *(float4*)(hrow + t * 4) = *(const float4*)(hs + (size_t)m * H_ + t * 4);
  __syncthreads();
  const int h = t & 31, pg = t >> 5;
  const float* wr = w1 + (size_t)(PROJ - HEADS + h) * H_ + pg * 128;
  const float* xr = hrow + pg * 128;
  float s = 0.f;
#pragma unroll 8
  for (int k = 0; k < 128; k += 4) {
    const float4 wv = *(const float4*)(wr + k);
    const float4 xv = *(const float4*)(xr + k);
    s += wv.x * xv.x + wv.y * xv.y + wv.z * xv.z + wv.w * xv.w;
  }
  part[h][pg] = s;
  __syncthreads();
  if (t < HEADS) {
    float z = dt_bias[t];
#pragma unroll
    for (int i = 0; i < 8; ++i) z += part[t][i];
    const float sp = z > 0.f ? z + log1pf(__expf(-z)) : log1pf(__expf(z));
    dtb[(size_t)m * HEADS + t] = sp;
  }
}

// ---------------- depthwise causal conv(K=4) + SiLU ----------------
__global__ __launch_bounds__(256) void conv_silu_k(
    const float* __restrict__ xbcf, const float* __restrict__ cw,
    const float* __restrict__ cbv,
    u16* __restrict__ xb16, float* __restrict__ Bbuf, float* __restrict__ Cbuf) {
  const int m = blockIdx.x;
  const int l = m & (L_ - 1);
  const int t = threadIdx.x;
  const float* pr = xbcf + (size_t)m * XBCW;
#pragma unroll
  for (int i = 0; i < 9; ++i) {
    const int ch = t + (i << 8);  // 0..2303
    float acc = cbv[ch];
    const float* w = cw + ch * 4;
#pragma unroll
    for (int k = 0; k < 4; ++k) {
      const int d = k - 3;
      if (l + d >= 0) acc += w[k] * pr[(long)d * XBCW + ch];
    }
    const float v = acc / (1.f + __expf(-acc));
    if (ch < INTER) xb16[(size_t)m * INTER + ch] = f2bf(v);
    else if (ch < INTER + NSTATE) Bbuf[(size_t)m * NSTATE + (ch - INTER)] = v;
    else Cbuf[(size_t)m * NSTATE + (ch - INTER - NSTATE)] = v;
  }
}

// ---------------- per-(b,c,h) dt chunk sums ----------------
__global__ void dtsum_k(const float* __restrict__ dtb, float* __restrict__ dts) {
  const int idx = blockIdx.x * 256 + threadIdx.x;  // (b*NC+c)*HEADS+h, 1024 total
  const int h = idx & 31, c = (idx >> 5) & 15, b = idx >> 9;
  const float* p = dtb + (size_t)(b * L_ + c * CHUNK) * HEADS + h;
  float s = 0.f;
  for (int i = 0; i < CHUNK; ++i) s += p[(size_t)i * HEADS];
  dts[idx] = s;
}

// ---------------- CB[l][s] = <C_l, B_s> per chunk (head-shared) ----------------
__global__ __launch_bounds__(256) void cb_k(
    const float* __restrict__ Bbuf, const float* __restrict__ Cbuf,
    float* __restrict__ CBb) {
  __shared__ float crow[NSTATE];
  const int bx = blockIdx.x;  // token index of row l
  const int t = threadIdx.x;
  if (t < NSTATE) crow[t] = Cbuf[(size_t)bx * NSTATE + t];
  __syncthreads();
  const int cbase = bx & ~(CHUNK - 1);
  const float* Brow = Bbuf + (size_t)(cbase + t) * NSTATE;
  float s = 0.f;
#pragma unroll 8
  for (int n = 0; n < NSTATE; n += 4) {
    const float4 bv = *(const float4*)(Brow + n);
    const float4 cv = *(const float4*)(crow + n);
    s += bv.x * cv.x + bv.y * cv.y + bv.z * cv.z + bv.w * cv.w;
  }
  CBb[(size_t)bx * CHUNK + t] = s;
}

// ---------------- Yd (intra-chunk) + chunk states via MFMA, per (b,c,h) ------
__global__ __launch_bounds__(512) void yd_states_k(
    const u16* __restrict__ xb16, const float* __restrict__ Bbuf,
    const float* __restrict__ dtb, const float* __restrict__ CBb,
    const float* __restrict__ A_log, u16* __restrict__ ydb16,
    float* __restrict__ states) {
  __shared__ float acs[CHUNK];
  __shared__ float dec[CHUNK];
  __shared__ u16 Xt[P_ * CHUNK];     // [p][s] bf16, elem ^= (p&7)<<3
  const int bx = blockIdx.x;
  const int h = bx & 31, c = (bx >> 5) & 15, b = bx >> 9;
  const int t = threadIdx.x;
  const int m0 = b * L_ + c * CHUNK;
  const float Ah = -__expf(A_log[h]);
  if (t < CHUNK) acs[t] = dtb[(size_t)(m0 + t) * HEADS + h];
  __syncthreads();
  {  // stage Xt = (x*dt)^T, bf16, swizzled; reads raw dt from acs[]
#pragma unroll
    for (int i = 0; i < 4; ++i) {
      const int s = i * 64 + (t >> 3);
      const int p0 = (t & 7) * 8;
      const float dtv = acs[s];
      const u16x8 v = *(const u16x8*)(xb16 + (size_t)(m0 + s) * INTER + h * P_ + p0);
#pragma unroll
      for (int j = 0; j < 8; ++j)
        Xt[((p0 + j) * CHUNK + s) ^ (j << 3)] = f2bf(bf2f(v[j]) * dtv);
    }
  }
  for (int off = 1; off < CHUNK; off <<= 1) {  // Hillis-Steele cumsum of dt
    float add = 0.f;
    if (t >= off && t < CHUNK) add = acs[t - off];
    __syncthreads();
    if (t >= off && t < CHUNK) acs[t] += add;
    __syncthreads();
  }
  {
    const float cum = (t < CHUNK) ? acs[t] : 0.f;
    const float tot = acs[CHUNK - 1];
    __syncthreads();
    if (t < CHUNK) {
      acs[t] = Ah * cum;                  // Acs (inclusive)
      dec[t] = __expf(Ah * (tot - cum));  // decay_states
    }
    __syncthreads();
  }
  const int lane = t & 63;
  const int wv = t >> 6;        // wave id 0..7
  const int fr = lane & 15;     // row/col within 16-tile
  const int fu = lane >> 4;     // k-subgroup 0..3
  {  // ---- states: n-tile = wv; D[p][n] over 4 p-tiles ----
    f32x4 acc_st[4] = {};
    const float* Bg = Bbuf + (size_t)m0 * NSTATE + wv * 16 + fr;
#pragma unroll 2
    for (int ks = 0; ks < 8; ++ks) {
      const int s0 = ks * 32 + fu * 8;
      u16x8 bw;
#pragma unroll
      for (int j = 0; j < 8; ++j)
        bw[j] = f2bf(Bg[(size_t)(s0 + j) * NSTATE] * dec[s0 + j]);
#pragma unroll
      for (int pt = 0; pt < 4; ++pt) {
        const int p = pt * 16 + fr;
        const u16x8 xa = *(const u16x8*)(Xt + ((p * CHUNK + s0) ^ ((p & 7) << 3)));
        acc_st[pt] = __builtin_amdgcn_mfma_f32_16x16x32_bf16(asbf(xa), asbf(bw), acc_st[pt], 0, 0, 0);
      }
    }
    float* sp = states + (size_t)((b * NC + c) * HEADS + h) * (P_ * NSTATE);
#pragma unroll
    for (int pt = 0; pt < 4; ++pt)
#pragma unroll
      for (int reg = 0; reg < 4; ++reg)
        sp[(size_t)(pt * 16 + fu * 4 + reg) * NSTATE + wv * 16 + fr] = acc_st[pt][reg];
  }
  {  // ---- Yd: l-tiles {wv, 15-wv} (balanced triangular work) ----
#pragma unroll
    for (int rep = 0; rep < 2; ++rep) {
      const int lt = rep ? (15 - wv) : wv;
      const int l = lt * 16 + fr;
      const float acl = acs[l];
      const float* cbr = CBb + (size_t)(m0 + l) * CHUNK;
      f32x4 acc_yd[4] = {};
      const int ksn = (lt >> 1) + 1;
      for (int ks = 0; ks < ksn; ++ks) {
        const int s0 = ks * 32 + fu * 8;
        const float4 cb0 = *(const float4*)(cbr + s0);
        const float4 cb1 = *(const float4*)(cbr + s0 + 4);
        u16x8 w8;
#pragma unroll
        for (int j = 0; j < 8; ++j) {
          const int s = s0 + j;
          const float cb = j < 4 ? ((const float*)&cb0)[j] : ((const float*)&cb1)[j - 4];
          const float w = (s <= l) ? cb * __expf(acl - acs[s]) : 0.f;
          w8[j] = f2bf(w);
        }
#pragma unroll
        for (int pt = 0; pt < 4; ++pt) {
          const int p = pt * 16 + fr;
          const u16x8 xb = *(const u16x8*)(Xt + ((p * CHUNK + s0) ^ ((p & 7) << 3)));
          acc_yd[pt] = __builtin_amdgcn_mfma_f32_16x16x32_bf16(asbf(w8), asbf(xb), acc_yd[pt], 0, 0, 0);
        }
      }
#pragma unroll
      for (int pt = 0; pt < 4; ++pt)
#pragma unroll
        for (int reg = 0; reg < 4; ++reg)
          ydb16[(size_t)(m0 + lt * 16 + fu * 4 + reg) * INTER + h * P_ + pt * 16 + fr] =
              f2bf(acc_yd[pt][reg]);
    }
  }
}

// ---------------- inter-chunk scan (states f32 -> prevb bf16) ----------------
__global__ void scan_k(const float* __restrict__ states, const float* __restrict__ dts,
                       const float* __restrict__ A_log, u16* __restrict__ prevb) {
  const int gid = blockIdx.x * 256 + threadIdx.x;  // over B_*HEADS*8192
  const int b = gid >> 18;
  const int h = (gid >> 13) & 31;
  const int pn = gid & 8191;
  const float Ah = -__expf(A_log[h]);
  float carry = 0.f;
  const size_t base = (size_t)b * (NC * HEADS * P_ * NSTATE) + (size_t)h * (P_ * NSTATE) + pn;
  const float* sp = states + base;
  u16* pp = prevb + base;
  for (int c = 0; c < NC; ++c) {
    const float dcv = __expf(Ah * dts[(b * NC + c) * HEADS + h]);
    const float st = sp[(size_t)c * (HEADS * P_ * NSTATE)];
    pp[(size_t)c * (HEADS * P_ * NSTATE)] = f2bf(carry);
    carry = carry * dcv + st;
  }
}

// ---------------- Yo via MFMA + Yd + D*x -> bf16 y ----------------
// Yo[l][p] = exp(Ah*acs[l]) * sum_n C[l][n] * prev[p][n]
__global__ __launch_bounds__(512) void yo_final_k(
    const u16* __restrict__ xb16, const float* __restrict__ Cbuf,
    const float* __restrict__ dtb, const u16* __restrict__ prevb,
    const float* __restrict__ A_log, const float* __restrict__ Dv,
    const u16* __restrict__ ydb16, u16* __restrict__ ybf) {
  __shared__ float acs[CHUNK];
  const int bx = blockIdx.x;
  const int h = bx & 31, c = (bx >> 5) & 15, b = bx >> 9;
  const int t = threadIdx.x;
  const int m0 = b * L_ + c * CHUNK;
  const float Ah = -__expf(A_log[h]);
  const float Dh = Dv[h];
  if (t < CHUNK) acs[t] = dtb[(size_t)(m0 + t) * HEADS + h];
  __syncthreads();
  for (int off = 1; off < CHUNK; off <<= 1) {
    float add = 0.f;
    if (t >= off && t < CHUNK) add = acs[t - off];
    __syncthreads();
    if (t >= off && t < CHUNK) acs[t] += add;
    __syncthreads();
  }
  const int lane = t & 63;
  const int wv = t >> 6;
  const int fr = lane & 15;
  const int fu = lane >> 4;
  // B-fragments: prev[p][n] rows are directly the B^T layout (k=n)
  const u16* pb = prevb + (size_t)((b * NC + c) * HEADS + h) * (P_ * NSTATE);
  u16x8 bfrag[4][4];  // [pt][ks]
#pragma unroll
  for (int pt = 0; pt < 4; ++pt)
#pragma unroll
    for (int ks = 0; ks < 4; ++ks)
      bfrag[pt][ks] = *(const u16x8*)(pb + (pt * 16 + fr) * NSTATE + ks * 32 + fu * 8);
#pragma unroll
  for (int rep = 0; rep < 2; ++rep) {
    const int lt = rep * 8 + wv;
    const float* cr = Cbuf + (size_t)(m0 + lt * 16 + fr) * NSTATE + fu * 8;
    f32x4 acc[4] = {};
#pragma unroll
    for (int ks = 0; ks < 4; ++ks) {
      const float4 c0 = *(const float4*)(cr + ks * 32);
      const float4 c1 = *(const float4*)(cr + ks * 32 + 4);
      const u16x8 a8 = { f2bf(c0.x), f2bf(c0.y), f2bf(c0.z), f2bf(c0.w),
                         f2bf(c1.x), f2bf(c1.y), f2bf(c1.z), f2bf(c1.w) };
#pragma unroll
      for (int pt = 0; pt < 4; ++pt)
        acc[pt] = __builtin_amdgcn_mfma_f32_16x16x32_bf16(asbf(a8), asbf(bfrag[pt][ks]), acc[pt], 0, 0, 0);
    }
#pragma unroll
    for (int reg = 0; reg < 4; ++reg) {
      const int l = lt * 16 + fu * 4 + reg;
      const float el = __expf(Ah * acs[l]);
      const size_t base = (size_t)(m0 + l) * INTER + h * P_;
#pragma unroll
      for (int pt = 0; pt < 4; ++pt) {
        const int p = pt * 16 + fr;
        const float yd = bf2f(ydb16[base + p]);
        const float xv = bf2f(xb16[base + p]);
        ybf[base + p] = f2bf(yd + el * acc[pt][reg] + Dh * xv);
      }
    }
  }
}

// ---------------- LayerNorm * SiLU(gate) -> bf16 ----------------
__global__ __launch_bounds__(256) void ln_gate_k(
    const u16* __restrict__ ybf, const u16* __restrict__ gateb,
    const float* __restrict__ lnw, const float* __restrict__ lnb,
    u16* __restrict__ yact) {
  __shared__ float red[8];
  const int m = blockIdx.x, t = threadIdx.x;
  const u16x8 yv = *(const u16x8*)(ybf + (size_t)m * INTER + t * 8);
  float y[8];
  float s = 0.f, ss = 0.f;
#pragma unroll
  for (int j = 0; j < 8; ++j) { y[j] = bf2f(yv[j]); s += y[j]; ss += y[j] * y[j]; }
#pragma unroll
  for (int off = 32; off > 0; off >>= 1) {
    s += __shfl_xor(s, off);
    ss += __shfl_xor(ss, off);
  }
  if ((t & 63) == 0) { red[(t >> 6) * 2] = s; red[(t >> 6) * 2 + 1] = ss; }
  __syncthreads();
  s = red[0] + red[2] + red[4] + red[6];
  ss = red[1] + red[3] + red[5] + red[7];
  const float mu = s * (1.f / INTER);
  const float rs = rsqrtf(ss * (1.f / INTER) - mu * mu + 1e-5f);
  const u16x8 gv = *(const u16x8*)(gateb + (size_t)m * INTER + t * 8);
  const float4 w0 = *(const float4*)(lnw + t * 8);
  const float4 w1 = *(const float4*)(lnw + t * 8 + 4);
  const float4 b0 = *(const float4*)(lnb + t * 8);
  const float4 b1 = *(const float4*)(lnb + t * 8 + 4);
  const float wj[8] = { w0.x, w0.y, w0.z, w0.w, w1.x, w1.y, w1.z, w1.w };
  const float bj[8] = { b0.x, b0.y, b0.z, b0.w, b1.x, b1.y, b1.z, b1.w };
  u16x8 o;
#pragma unroll
  for (int j = 0; j < 8; ++j) {
    const float g = bf2f(gv[j]);
    const float yn = (y[j] - mu) * rs * wj[j] + bj[j];
    const float sg = g / (1.f + __expf(-g));
    o[j] = f2bf(yn * sg);
  }
  *(u16x8*)(yact + (size_t)m * INTER + t * 8) = o;
}

// ---------------- launch ----------------
extern "C" void kernel_launch(void* const* d_in, const int* in_sizes, int n_in,
                              void* d_out, int out_size, void* d_ws, size_t ws_size,
                              hipStream_t stream) {
  (void)in_sizes; (void)n_in; (void)out_size; (void)ws_size;
  const float* hs     = (const float*)d_in[0];
  const float* w1     = (const float*)d_in[1];
  const float* cw     = (const float*)d_in[2];
  const float* cbv    = (const float*)d_in[3];
  const float* dtbias = (const float*)d_in[4];
  const float* alog   = (const float*)d_in[5];
  const float* Dv     = (const float*)d_in[6];
  const float* lnw    = (const float*)d_in[7];
  const float* lnb    = (const float*)d_in[8];
  const float* w2     = (const float*)d_in[9];
  float* out = (float*)d_out;
  char* ws = (char*)d_ws;
  size_t off = 0;
  auto alloc = [&](size_t bytes) {
    void* p = ws + off; off += (bytes + 255) & ~(size_t)255; return p;
  };
  // total ~210 MiB
  u16*   hb     = (u16*)alloc((size_t)MTOK * H_ * 2);        // 16.8 MiB; CBb then prevb alias
  float* CBb    = (float*)hb;                                //  8.4 MiB alias (dead after yd_states)
  u16*   prevb  = hb;                                        // 16.8 MiB alias (scan_k onward)
  u16*   w1b    = (u16*)alloc((size_t)PROJP * H_ * 2);       //  8.75 MiB
  u16*   w2b    = (u16*)alloc((size_t)H_ * INTER * 2);       //  4 MiB
  u16*   gateb  = (u16*)alloc((size_t)MTOK * INTER * 2);     // 32 MiB
  float* xbcf   = (float*)alloc((size_t)MTOK * XBCW * 4);    // 76 MiB; ydb16+ybf alias after conv
  u16*   ydb16  = (u16*)xbcf;                                // 32 MiB alias
  u16*   ybf    = (u16*)((char*)xbcf + ((size_t)MTOK * INTER * 2)); // next 32 MiB
  u16*   xb16   = (u16*)alloc((size_t)MTOK * INTER * 2);     // 32 MiB; yact aliases after yo_final
  u16*   yact   = xb16;
  float* Bbuf   = (float*)alloc((size_t)MTOK * NSTATE * 4);  //  4 MiB
  float* Cbuf   = (float*)alloc((size_t)MTOK * NSTATE * 4);  //  4 MiB
  float* dtb    = (float*)alloc((size_t)MTOK * HEADS * 4);   //  1 MiB
  float* dts    = (float*)alloc(1024 * 4);
  float* states = (float*)alloc((size_t)B_ * NC * HEADS * P_ * NSTATE * 4);  // 32 MiB

  cast_bf16_k<<<MTOK * H_ / 1024, 256, 0, stream>>>(hs, hb);
  cast_w1_k<<<PROJP * H_ / 1024, 256, 0, stream>>>(w1, w1b);
  cast_bf16_k<<<H_ * INTER / 1024, 256, 0, stream>>>(w2, w2b);
  dtproj_k<<<MTOK, 256, 0, stream>>>(hs, w1, dtbias, dtb);
  gemm_bt_k<1><<<dim3(PROJP / 128, MTOK / 128), 256, 0, stream>>>(
      hb, w1b, nullptr, gateb, xbcf, H_, 0);
  conv_silu_k<<<MTOK, 256, 0, stream>>>(xbcf, cw, cbv, xb16, Bbuf, Cbuf);
  dtsum_k<<<4, 256, 0, stream>>>(dtb, dts);
  cb_k<<<MTOK, 256, 0, stream>>>(Bbuf, Cbuf, CBb);
  yd_states_k<<<B_ * NC * HEADS, 512, 0, stream>>>(xb16, Bbuf, dtb, CBb, alog, ydb16, states);
  scan_k<<<B_ * HEADS * P_ * NSTATE / 256, 256, 0, stream>>>(states, dts, alog, prevb);
  yo_final_k<<<B_ * NC * HEADS, 512, 0, stream>>>(xb16, Cbuf, dtb, prevb, alog, Dv, ydb16, ybf);
  ln_gate_k<<<MTOK, 256, 0, stream>>>(ybf, gateb, lnw, lnb, yact);
  gemm_bt_k<0><<<dim3(H_ / 128, MTOK / 128), 256, 0, stream>>>(
      yact, w2b, out, nullptr, nullptr, INTER, H_);
}

// Round 7
// 501.430 us; speedup vs baseline: 2.0106x; 1.3833x over previous
//
#include <hip/hip_runtime.h>

typedef unsigned short u16;
typedef u16 u16x4 __attribute__((ext_vector_type(4)));
typedef u16 u16x8 __attribute__((ext_vector_type(8)));
typedef __bf16 bf16x8 __attribute__((ext_vector_type(8)));
typedef float f32x4 __attribute__((ext_vector_type(4)));

#define B_    2
#define L_    4096
#define H_    1024
#define INTER 2048
#define NSTATE 128
#define HEADS 32
#define P_    64
#define CHUNK 256
#define NC    16
#define CONVD 2304
#define PROJ  4384
#define PROJP 4480     // padded N for GEMM tiles (35 x 128)
#define XBCW  2432     // xBC f32 buffer width (PROJP - 2048)
#define MTOK  8192     // B_*L_

__device__ __forceinline__ u16 f2bf(float f) {
  unsigned u = __float_as_uint(f);
  u += 0x7fffu + ((u >> 16) & 1u);   // RNE
  return (u16)(u >> 16);
}
__device__ __forceinline__ float bf2f(u16 u) {
  return __uint_as_float(((unsigned)u) << 16);
}
__device__ __forceinline__ bf16x8 asbf(u16x8 v) {
  union { u16x8 u; bf16x8 b; } x; x.u = v; return x.b;
}

// ---------------- casts ----------------
__global__ void cast_bf16_k(const float* __restrict__ in, u16* __restrict__ out) {
  size_t i = ((size_t)blockIdx.x * 256 + threadIdx.x) * 4;
  float4 v = *(const float4*)(in + i);
  u16x4 o = { f2bf(v.x), f2bf(v.y), f2bf(v.z), f2bf(v.w) };
  *(u16x4*)(out + i) = o;
}

__global__ void cast_w1_k(const float* __restrict__ in, u16* __restrict__ out) {
  size_t i = ((size_t)blockIdx.x * 256 + threadIdx.x) * 4;
  u16x4 o = { 0, 0, 0, 0 };
  if (i < (size_t)PROJ * H_) {
    float4 v = *(const float4*)(in + i);
    o = (u16x4){ f2bf(v.x), f2bf(v.y), f2bf(v.z), f2bf(v.w) };
  }
  *(u16x4*)(out + i) = o;   // rows 4384..4479 zero-padded
}

// ---------------- bf16 MFMA GEMM: C[M,N] = A[M,K] * B[N,K]^T ----------------
// SPLIT=0: plain f32 C (ldc). SPLIT=1: cols<2048 -> bf16 gateb, else f32 xbcf.
template<int SPLIT>
__global__ __launch_bounds__(256) void gemm_bt_k(
    const u16* __restrict__ A, const u16* __restrict__ Bm, float* __restrict__ C,
    u16* __restrict__ gateb, float* __restrict__ xbcf,
    const int K, const int ldc) {
  __shared__ u16 Als[4096];
  __shared__ u16 Bls[4096];
  const int tid = threadIdx.x;
  const int bn = blockIdx.x, bm = blockIdx.y;
  const u16* Ab = A + (size_t)bm * 128 * K;
  const u16* Bb = Bm + (size_t)bn * 128 * K;
  const int row = tid >> 2, col = (tid & 3) << 3;
  const int lane = tid & 63;
  const int wr = ((tid >> 7) & 1) << 6;
  const int wc = ((tid >> 6) & 1) << 6;
  const int fr = lane & 15;
  const int fk = (lane >> 4) << 3;
  f32x4 acc[4][4] = {};
  const size_t rA0 = (size_t)row * K + col, rA1 = (size_t)(row + 64) * K + col;
  u16x8 ra0 = *(const u16x8*)(Ab + rA0);
  u16x8 ra1 = *(const u16x8*)(Ab + rA1);
  u16x8 rb0 = *(const u16x8*)(Bb + rA0);
  u16x8 rb1 = *(const u16x8*)(Bb + rA1);
  const int nk = K >> 5;
  for (int kt = 0; kt < nk; ++kt) {
    *(u16x8*)(Als + tid * 8) = ra0;
    *(u16x8*)(Als + 2048 + tid * 8) = ra1;
    *(u16x8*)(Bls + tid * 8) = rb0;
    *(u16x8*)(Bls + 2048 + tid * 8) = rb1;
    __syncthreads();
    if (kt + 1 < nk) {
      const size_t ko = (size_t)(kt + 1) * 32;
      ra0 = *(const u16x8*)(Ab + rA0 + ko);
      ra1 = *(const u16x8*)(Ab + rA1 + ko);
      rb0 = *(const u16x8*)(Bb + rA0 + ko);
      rb1 = *(const u16x8*)(Bb + rA1 + ko);
    }
    bf16x8 af[4], bfv[4];
#pragma unroll
    for (int m = 0; m < 4; ++m)
      af[m] = asbf(*(const u16x8*)(Als + (wr + m * 16 + fr) * 32 + fk));
#pragma unroll
    for (int n = 0; n < 4; ++n)
      bfv[n] = asbf(*(const u16x8*)(Bls + (wc + n * 16 + fr) * 32 + fk));
#pragma unroll
    for (int m = 0; m < 4; ++m)
#pragma unroll
      for (int n = 0; n < 4; ++n)
        acc[m][n] = __builtin_amdgcn_mfma_f32_16x16x32_bf16(af[m], bfv[n], acc[m][n], 0, 0, 0);
    __syncthreads();
  }
  const int crow = bm * 128 + wr + ((lane >> 4) << 2);
  if (SPLIT == 0) {
    float* Cp = C + (size_t)crow * ldc + bn * 128 + wc + fr;
#pragma unroll
    for (int m = 0; m < 4; ++m)
#pragma unroll
      for (int n = 0; n < 4; ++n)
#pragma unroll
        for (int j = 0; j < 4; ++j)
          Cp[(size_t)(m * 16 + j) * ldc + n * 16] = acc[m][n][j];
  } else if (bn < 16) {   // gate columns -> bf16
    u16* Gp = gateb + (size_t)crow * INTER + bn * 128 + wc + fr;
#pragma unroll
    for (int m = 0; m < 4; ++m)
#pragma unroll
      for (int n = 0; n < 4; ++n)
#pragma unroll
        for (int j = 0; j < 4; ++j)
          Gp[(size_t)(m * 16 + j) * INTER + n * 16] = f2bf(acc[m][n][j]);
  } else {                // xBC (+dt tail, unused) columns -> f32
    float* Xp = xbcf + (size_t)crow * XBCW + (bn - 16) * 128 + wc + fr;
#pragma unroll
    for (int m = 0; m < 4; ++m)
#pragma unroll
      for (int n = 0; n < 4; ++n)
#pragma unroll
        for (int j = 0; j < 4; ++j)
          Xp[(size_t)(m * 16 + j) * XBCW + n * 16] = acc[m][n][j];
  }
}

// ---------------- exact f32 dt partials: split-K, w-stationary ----------------
// grid (4 ksplit, 256 m-tiles of 32 tokens); part[ks][m][h] f32
__global__ __launch_bounds__(256) void dtpart_k(
    const float* __restrict__ hs, const float* __restrict__ w1,
    float* __restrict__ part) {
  __shared__ float hls[32 * 256];       // 32 KB
  __shared__ float wq[32 * 8 * 32];     // 32 KB  [tok][q][h]
  const int ks = blockIdx.x, mt = blockIdx.y;
  const int m0 = mt * 32;
  const int t = threadIdx.x;
  const int h = t & 31, q = t >> 5;
  // w-slice in registers: w1[(4352+h)][ks*256 + q*32 .. +32]
  float w[32];
  {
    const float* wp = w1 + (size_t)(PROJ - HEADS + h) * H_ + ks * 256 + q * 32;
#pragma unroll
    for (int i = 0; i < 8; ++i) {
      const float4 v = *(const float4*)(wp + i * 4);
      w[i * 4] = v.x; w[i * 4 + 1] = v.y; w[i * 4 + 2] = v.z; w[i * 4 + 3] = v.w;
    }
  }
  // stage hs[32 tokens][256 cols of this ksplit]
#pragma unroll
  for (int i = 0; i < 8; ++i) {
    const int idx = i * 1024 + t * 4;
    const int row = idx >> 8, col = idx & 255;
    *(float4*)(hls + idx) = *(const float4*)(hs + (size_t)(m0 + row) * H_ + ks * 256 + col);
  }
  __syncthreads();
  for (int tok = 0; tok < 32; ++tok) {
    const float* hp = hls + tok * 256 + q * 32;
    float s = 0.f;
#pragma unroll
    for (int i = 0; i < 8; ++i) {
      const float4 hv = *(const float4*)(hp + i * 4);
      s += w[i * 4] * hv.x + w[i * 4 + 1] * hv.y + w[i * 4 + 2] * hv.z + w[i * 4 + 3] * hv.w;
    }
    wq[tok * 256 + q * 32 + h] = s;
  }
  __syncthreads();
#pragma unroll
  for (int i = 0; i < 4; ++i) {
    const int idx = i * 256 + t;
    const int tok = idx >> 5, h2 = idx & 31;
    float s = 0.f;
#pragma unroll
    for (int qq = 0; qq < 8; ++qq) s += wq[tok * 256 + qq * 32 + h2];
    part[((size_t)ks * MTOK + m0 + tok) * HEADS + h2] = s;
  }
}

// ---------------- dt finalize: sum ksplits + bias, softplus ----------------
__global__ __launch_bounds__(256) void dtfin_k(
    const float* __restrict__ part, const float* __restrict__ dt_bias,
    float* __restrict__ dtb) {
  const int gid = blockIdx.x * 256 + threadIdx.x;   // over MTOK*HEADS
  const int h = gid & 31;
  float z = dt_bias[h];
#pragma unroll
  for (int ks = 0; ks < 4; ++ks) z += part[(size_t)ks * MTOK * HEADS + gid];
  const float sp = z > 0.f ? z + log1pf(__expf(-z)) : log1pf(__expf(z));
  dtb[gid] = sp;
}

// ---------------- depthwise causal conv(K=4) + SiLU ----------------
__global__ __launch_bounds__(256) void conv_silu_k(
    const float* __restrict__ xbcf, const float* __restrict__ cw,
    const float* __restrict__ cbv,
    u16* __restrict__ xb16, float* __restrict__ Bbuf, float* __restrict__ Cbuf) {
  const int m = blockIdx.x;
  const int l = m & (L_ - 1);
  const int t = threadIdx.x;
  const float* pr = xbcf + (size_t)m * XBCW;
#pragma unroll
  for (int i = 0; i < 9; ++i) {
    const int ch = t + (i << 8);  // 0..2303
    float acc = cbv[ch];
    const float* w = cw + ch * 4;
#pragma unroll
    for (int k = 0; k < 4; ++k) {
      const int d = k - 3;
      if (l + d >= 0) acc += w[k] * pr[(long)d * XBCW + ch];
    }
    const float v = acc / (1.f + __expf(-acc));
    if (ch < INTER) xb16[(size_t)m * INTER + ch] = f2bf(v);
    else if (ch < INTER + NSTATE) Bbuf[(size_t)m * NSTATE + (ch - INTER)] = v;
    else Cbuf[(size_t)m * NSTATE + (ch - INTER - NSTATE)] = v;
  }
}

// ---------------- per-(b,c,h) dt chunk sums ----------------
__global__ void dtsum_k(const float* __restrict__ dtb, float* __restrict__ dts) {
  const int idx = blockIdx.x * 256 + threadIdx.x;  // (b*NC+c)*HEADS+h, 1024 total
  const int h = idx & 31, c = (idx >> 5) & 15, b = idx >> 9;
  const float* p = dtb + (size_t)(b * L_ + c * CHUNK) * HEADS + h;
  float s = 0.f;
  for (int i = 0; i < CHUNK; ++i) s += p[(size_t)i * HEADS];
  dts[idx] = s;
}

// ---------------- CB = C_chunk * B_chunk^T via MFMA, per (b,c) --------------
__global__ __launch_bounds__(512) void cb_k(
    const float* __restrict__ Bbuf, const float* __restrict__ Cbuf,
    float* __restrict__ CBb) {
  __shared__ u16 Bls[CHUNK * NSTATE];   // 64 KB, swizzled: elem ^= (row&7)<<3
  const int bx = blockIdx.x;            // chunk index (b*NC+c), m0 = bx*256
  const int m0 = bx * CHUNK;
  const int t = threadIdx.x;
  // stage B chunk -> bf16 swizzled
#pragma unroll
  for (int i = 0; i < 16; ++i) {
    const int idx = i * 2048 + t * 4;
    const int row = idx >> 7;
    const float4 v = *(const float4*)(Bbuf + (size_t)m0 * NSTATE + idx);
    u16x4 o = { f2bf(v.x), f2bf(v.y), f2bf(v.z), f2bf(v.w) };
    *(u16x4*)(Bls + (idx ^ ((row & 7) << 3))) = o;
  }
  __syncthreads();
  const int lane = t & 63, wv = t >> 6;
  const int fr = lane & 15, fu = lane >> 4;
  // A-fragments from C rows (global, L2-hot), rt in {wv, wv+8}
  u16x8 afrag[2][4];
#pragma unroll
  for (int r = 0; r < 2; ++r) {
    const int row = (wv + r * 8) * 16 + fr;
    const float* cp = Cbuf + (size_t)(m0 + row) * NSTATE + fu * 8;
#pragma unroll
    for (int ks = 0; ks < 4; ++ks) {
      const float4 c0 = *(const float4*)(cp + ks * 32);
      const float4 c1 = *(const float4*)(cp + ks * 32 + 4);
      afrag[r][ks] = (u16x8){ f2bf(c0.x), f2bf(c0.y), f2bf(c0.z), f2bf(c0.w),
                              f2bf(c1.x), f2bf(c1.y), f2bf(c1.z), f2bf(c1.w) };
    }
  }
  for (int ct = 0; ct < 16; ++ct) {
    u16x8 bfrag[4];
#pragma unroll
    for (int ks = 0; ks < 4; ++ks)
      bfrag[ks] = *(const u16x8*)(Bls + (((ct * 16 + fr) * NSTATE + ks * 32 + fu * 8)
                                         ^ ((fr & 7) << 3)));
    f32x4 acc[2] = {};
#pragma unroll
    for (int r = 0; r < 2; ++r)
#pragma unroll
      for (int ks = 0; ks < 4; ++ks)
        acc[r] = __builtin_amdgcn_mfma_f32_16x16x32_bf16(asbf(afrag[r][ks]), asbf(bfrag[ks]), acc[r], 0, 0, 0);
#pragma unroll
    for (int r = 0; r < 2; ++r) {
      const int rowb = (wv + r * 8) * 16 + fu * 4;
#pragma unroll
      for (int reg = 0; reg < 4; ++reg)
        CBb[(size_t)(m0 + rowb + reg) * CHUNK + ct * 16 + fr] = acc[r][reg];
    }
  }
}

// ---------------- Yd (intra-chunk) + chunk states via MFMA, per (b,c,h) ------
__global__ __launch_bounds__(512) void yd_states_k(
    const u16* __restrict__ xb16, const float* __restrict__ Bbuf,
    const float* __restrict__ dtb, const float* __restrict__ CBb,
    const float* __restrict__ A_log, u16* __restrict__ ydb16,
    float* __restrict__ states) {
  __shared__ float acs[CHUNK];
  __shared__ float dec[CHUNK];
  __shared__ u16 Xt[P_ * CHUNK];     // [p][s] bf16, elem ^= (p&7)<<3
  const int bx = blockIdx.x;
  const int h = bx & 31, c = (bx >> 5) & 15, b = bx >> 9;
  const int t = threadIdx.x;
  const int m0 = b * L_ + c * CHUNK;
  const float Ah = -__expf(A_log[h]);
  if (t < CHUNK) acs[t] = dtb[(size_t)(m0 + t) * HEADS + h];
  __syncthreads();
  {  // stage Xt = (x*dt)^T, bf16, swizzled; reads raw dt from acs[]
#pragma unroll
    for (int i = 0; i < 4; ++i) {
      const int s = i * 64 + (t >> 3);
      const int p0 = (t & 7) * 8;
      const float dtv = acs[s];
      const u16x8 v = *(const u16x8*)(xb16 + (size_t)(m0 + s) * INTER + h * P_ + p0);
#pragma unroll
      for (int j = 0; j < 8; ++j)
        Xt[((p0 + j) * CHUNK + s) ^ (j << 3)] = f2bf(bf2f(v[j]) * dtv);
    }
  }
  for (int off = 1; off < CHUNK; off <<= 1) {  // Hillis-Steele cumsum of dt
    float add = 0.f;
    if (t >= off && t < CHUNK) add = acs[t - off];
    __syncthreads();
    if (t >= off && t < CHUNK) acs[t] += add;
    __syncthreads();
  }
  {
    const float cum = (t < CHUNK) ? acs[t] : 0.f;
    const float tot = acs[CHUNK - 1];
    __syncthreads();
    if (t < CHUNK) {
      acs[t] = Ah * cum;                  // Acs (inclusive)
      dec[t] = __expf(Ah * (tot - cum));  // decay_states
    }
    __syncthreads();
  }
  const int lane = t & 63;
  const int wv = t >> 6;        // wave id 0..7
  const int fr = lane & 15;     // row/col within 16-tile
  const int fu = lane >> 4;     // k-subgroup 0..3
  {  // ---- states: n-tile = wv; D[p][n] over 4 p-tiles ----
    f32x4 acc_st[4] = {};
    const float* Bg = Bbuf + (size_t)m0 * NSTATE + wv * 16 + fr;
#pragma unroll 2
    for (int ks = 0; ks < 8; ++ks) {
      const int s0 = ks * 32 + fu * 8;
      u16x8 bw;
#pragma unroll
      for (int j = 0; j < 8; ++j)
        bw[j] = f2bf(Bg[(size_t)(s0 + j) * NSTATE] * dec[s0 + j]);
#pragma unroll
      for (int pt = 0; pt < 4; ++pt) {
        const int p = pt * 16 + fr;
        const u16x8 xa = *(const u16x8*)(Xt + ((p * CHUNK + s0) ^ ((p & 7) << 3)));
        acc_st[pt] = __builtin_amdgcn_mfma_f32_16x16x32_bf16(asbf(xa), asbf(bw), acc_st[pt], 0, 0, 0);
      }
    }
    float* sp = states + (size_t)((b * NC + c) * HEADS + h) * (P_ * NSTATE);
#pragma unroll
    for (int pt = 0; pt < 4; ++pt)
#pragma unroll
      for (int reg = 0; reg < 4; ++reg)
        sp[(size_t)(pt * 16 + fu * 4 + reg) * NSTATE + wv * 16 + fr] = acc_st[pt][reg];
  }
  {  // ---- Yd: l-tiles {wv, 15-wv} (balanced triangular work) ----
#pragma unroll
    for (int rep = 0; rep < 2; ++rep) {
      const int lt = rep ? (15 - wv) : wv;
      const int l = lt * 16 + fr;
      const float acl = acs[l];
      const float* cbr = CBb + (size_t)(m0 + l) * CHUNK;
      f32x4 acc_yd[4] = {};
      const int ksn = (lt >> 1) + 1;
      for (int ks = 0; ks < ksn; ++ks) {
        const int s0 = ks * 32 + fu * 8;
        const float4 cb0 = *(const float4*)(cbr + s0);
        const float4 cb1 = *(const float4*)(cbr + s0 + 4);
        u16x8 w8;
#pragma unroll
        for (int j = 0; j < 8; ++j) {
          const int s = s0 + j;
          const float cb = j < 4 ? ((const float*)&cb0)[j] : ((const float*)&cb1)[j - 4];
          const float w = (s <= l) ? cb * __expf(acl - acs[s]) : 0.f;
          w8[j] = f2bf(w);
        }
#pragma unroll
        for (int pt = 0; pt < 4; ++pt) {
          const int p = pt * 16 + fr;
          const u16x8 xb = *(const u16x8*)(Xt + ((p * CHUNK + s0) ^ ((p & 7) << 3)));
          acc_yd[pt] = __builtin_amdgcn_mfma_f32_16x16x32_bf16(asbf(w8), asbf(xb), acc_yd[pt], 0, 0, 0);
        }
      }
#pragma unroll
      for (int pt = 0; pt < 4; ++pt)
#pragma unroll
        for (int reg = 0; reg < 4; ++reg)
          ydb16[(size_t)(m0 + lt * 16 + fu * 4 + reg) * INTER + h * P_ + pt * 16 + fr] =
              f2bf(acc_yd[pt][reg]);
    }
  }
}

// ---------------- inter-chunk scan (states f32 -> prevb bf16) ----------------
__global__ void scan_k(const float* __restrict__ states, const float* __restrict__ dts,
                       const float* __restrict__ A_log, u16* __restrict__ prevb) {
  const int gid = blockIdx.x * 256 + threadIdx.x;  // over B_*HEADS*8192
  const int b = gid >> 18;
  const int h = (gid >> 13) & 31;
  const int pn = gid & 8191;
  const float Ah = -__expf(A_log[h]);
  float carry = 0.f;
  const size_t base = (size_t)b * (NC * HEADS * P_ * NSTATE) + (size_t)h * (P_ * NSTATE) + pn;
  const float* sp = states + base;
  u16* pp = prevb + base;
  for (int c = 0; c < NC; ++c) {
    const float dcv = __expf(Ah * dts[(b * NC + c) * HEADS + h]);
    const float st = sp[(size_t)c * (HEADS * P_ * NSTATE)];
    pp[(size_t)c * (HEADS * P_ * NSTATE)] = f2bf(carry);
    carry = carry * dcv + st;
  }
}

// ---------------- Yo via MFMA + Yd + D*x -> bf16 y ----------------
__global__ __launch_bounds__(512) void yo_final_k(
    const u16* __restrict__ xb16, const float* __restrict__ Cbuf,
    const float* __restrict__ dtb, const u16* __restrict__ prevb,
    const float* __restrict__ A_log, const float* __restrict__ Dv,
    const u16* __restrict__ ydb16, u16* __restrict__ ybf) {
  __shared__ float acs[CHUNK];
  const int bx = blockIdx.x;
  const int h = bx & 31, c = (bx >> 5) & 15, b = bx >> 9;
  const int t = threadIdx.x;
  const int m0 = b * L_ + c * CHUNK;
  const float Ah = -__expf(A_log[h]);
  const float Dh = Dv[h];
  if (t < CHUNK) acs[t] = dtb[(size_t)(m0 + t) * HEADS + h];
  __syncthreads();
  for (int off = 1; off < CHUNK; off <<= 1) {
    float add = 0.f;
    if (t >= off && t < CHUNK) add = acs[t - off];
    __syncthreads();
    if (t >= off && t < CHUNK) acs[t] += add;
    __syncthreads();
  }
  const int lane = t & 63;
  const int wv = t >> 6;
  const int fr = lane & 15;
  const int fu = lane >> 4;
  const u16* pb = prevb + (size_t)((b * NC + c) * HEADS + h) * (P_ * NSTATE);
  u16x8 bfrag[4][4];  // [pt][ks]
#pragma unroll
  for (int pt = 0; pt < 4; ++pt)
#pragma unroll
    for (int ks = 0; ks < 4; ++ks)
      bfrag[pt][ks] = *(const u16x8*)(pb + (pt * 16 + fr) * NSTATE + ks * 32 + fu * 8);
#pragma unroll
  for (int rep = 0; rep < 2; ++rep) {
    const int lt = rep * 8 + wv;
    const float* cr = Cbuf + (size_t)(m0 + lt * 16 + fr) * NSTATE + fu * 8;
    f32x4 acc[4] = {};
#pragma unroll
    for (int ks = 0; ks < 4; ++ks) {
      const float4 c0 = *(const float4*)(cr + ks * 32);
      const float4 c1 = *(const float4*)(cr + ks * 32 + 4);
      const u16x8 a8 = { f2bf(c0.x), f2bf(c0.y), f2bf(c0.z), f2bf(c0.w),
                         f2bf(c1.x), f2bf(c1.y), f2bf(c1.z), f2bf(c1.w) };
#pragma unroll
      for (int pt = 0; pt < 4; ++pt)
        acc[pt] = __builtin_amdgcn_mfma_f32_16x16x32_bf16(asbf(a8), asbf(bfrag[pt][ks]), acc[pt], 0, 0, 0);
    }
#pragma unroll
    for (int reg = 0; reg < 4; ++reg) {
      const int l = lt * 16 + fu * 4 + reg;
      const float el = __expf(Ah * acs[l]);
      const size_t base = (size_t)(m0 + l) * INTER + h * P_;
#pragma unroll
      for (int pt = 0; pt < 4; ++pt) {
        const int p = pt * 16 + fr;
        const float yd = bf2f(ydb16[base + p]);
        const float xv = bf2f(xb16[base + p]);
        ybf[base + p] = f2bf(yd + el * acc[pt][reg] + Dh * xv);
      }
    }
  }
}

// ---------------- LayerNorm * SiLU(gate) -> bf16 ----------------
__global__ __launch_bounds__(256) void ln_gate_k(
    const u16* __restrict__ ybf, const u16* __restrict__ gateb,
    const float* __restrict__ lnw, const float* __restrict__ lnb,
    u16* __restrict__ yact) {
  __shared__ float red[8];
  const int m = blockIdx.x, t = threadIdx.x;
  const u16x8 yv = *(const u16x8*)(ybf + (size_t)m * INTER + t * 8);
  float y[8];
  float s = 0.f, ss = 0.f;
#pragma unroll
  for (int j = 0; j < 8; ++j) { y[j] = bf2f(yv[j]); s += y[j]; ss += y[j] * y[j]; }
#pragma unroll
  for (int off = 32; off > 0; off >>= 1) {
    s += __shfl_xor(s, off);
    ss += __shfl_xor(ss, off);
  }
  if ((t & 63) == 0) { red[(t >> 6) * 2] = s; red[(t >> 6) * 2 + 1] = ss; }
  __syncthreads();
  s = red[0] + red[2] + red[4] + red[6];
  ss = red[1] + red[3] + red[5] + red[7];
  const float mu = s * (1.f / INTER);
  const float rs = rsqrtf(ss * (1.f / INTER) - mu * mu + 1e-5f);
  const u16x8 gv = *(const u16x8*)(gateb + (size_t)m * INTER + t * 8);
  const float4 w0 = *(const float4*)(lnw + t * 8);
  const float4 w1 = *(const float4*)(lnw + t * 8 + 4);
  const float4 b0 = *(const float4*)(lnb + t * 8);
  const float4 b1 = *(const float4*)(lnb + t * 8 + 4);
  const float wj[8] = { w0.x, w0.y, w0.z, w0.w, w1.x, w1.y, w1.z, w1.w };
  const float bj[8] = { b0.x, b0.y, b0.z, b0.w, b1.x, b1.y, b1.z, b1.w };
  u16x8 o;
#pragma unroll
  for (int j = 0; j < 8; ++j) {
    const float g = bf2f(gv[j]);
    const float yn = (y[j] - mu) * rs * wj[j] + bj[j];
    const float sg = g / (1.f + __expf(-g));
    o[j] = f2bf(yn * sg);
  }
  *(u16x8*)(yact + (size_t)m * INTER + t * 8) = o;
}

// ---------------- launch ----------------
extern "C" void kernel_launch(void* const* d_in, const int* in_sizes, int n_in,
                              void* d_out, int out_size, void* d_ws, size_t ws_size,
                              hipStream_t stream) {
  (void)in_sizes; (void)n_in; (void)out_size; (void)ws_size;
  const float* hs     = (const float*)d_in[0];
  const float* w1     = (const float*)d_in[1];
  const float* cw     = (const float*)d_in[2];
  const float* cbv    = (const float*)d_in[3];
  const float* dtbias = (const float*)d_in[4];
  const float* alog   = (const float*)d_in[5];
  const float* Dv     = (const float*)d_in[6];
  const float* lnw    = (const float*)d_in[7];
  const float* lnb    = (const float*)d_in[8];
  const float* w2     = (const float*)d_in[9];
  float* out = (float*)d_out;
  char* ws = (char*)d_ws;
  size_t off = 0;
  auto alloc = [&](size_t bytes) {
    void* p = ws + off; off += (bytes + 255) & ~(size_t)255; return p;
  };
  u16*   hb     = (u16*)alloc((size_t)MTOK * H_ * 2);        // 16.8 MiB; CBb then prevb alias
  float* CBb    = (float*)hb;                                //  8.4 MiB alias (dead after yd_states)
  u16*   prevb  = hb;                                        // 16.8 MiB alias (scan_k onward)
  u16*   w1b    = (u16*)alloc((size_t)PROJP * H_ * 2);       //  8.75 MiB
  u16*   w2b    = (u16*)alloc((size_t)H_ * INTER * 2);       //  4 MiB
  u16*   gateb  = (u16*)alloc((size_t)MTOK * INTER * 2);     // 32 MiB
  float* xbcf   = (float*)alloc((size_t)MTOK * XBCW * 4);    // 76 MiB; ydb16+ybf alias after conv
  u16*   ydb16  = (u16*)xbcf;                                // 32 MiB alias
  u16*   ybf    = (u16*)((char*)xbcf + ((size_t)MTOK * INTER * 2)); // next 32 MiB
  u16*   xb16   = (u16*)alloc((size_t)MTOK * INTER * 2);     // 32 MiB; yact aliases after yo_final
  u16*   yact   = xb16;
  float* Bbuf   = (float*)alloc((size_t)MTOK * NSTATE * 4);  //  4 MiB
  float* Cbuf   = (float*)alloc((size_t)MTOK * NSTATE * 4);  //  4 MiB
  float* dtb    = (float*)alloc((size_t)MTOK * HEADS * 4);   //  1 MiB
  float* dts    = (float*)alloc(1024 * 4);
  float* states = (float*)alloc((size_t)B_ * NC * HEADS * P_ * NSTATE * 4);  // 32 MiB
  float* part   = states;   // 4 MiB alias (dtpart/dtfin, dead before yd_states)

  cast_bf16_k<<<MTOK * H_ / 1024, 256, 0, stream>>>(hs, hb);
  cast_w1_k<<<PROJP * H_ / 1024, 256, 0, stream>>>(w1, w1b);
  cast_bf16_k<<<H_ * INTER / 1024, 256, 0, stream>>>(w2, w2b);
  dtpart_k<<<dim3(4, MTOK / 32), 256, 0, stream>>>(hs, w1, part);
  dtfin_k<<<MTOK * HEADS / 256, 256, 0, stream>>>(part, dtbias, dtb);
  gemm_bt_k<1><<<dim3(PROJP / 128, MTOK / 128), 256, 0, stream>>>(
      hb, w1b, nullptr, gateb, xbcf, H_, 0);
  conv_silu_k<<<MTOK, 256, 0, stream>>>(xbcf, cw, cbv, xb16, Bbuf, Cbuf);
  dtsum_k<<<4, 256, 0, stream>>>(dtb, dts);
  cb_k<<<B_ * NC, 512, 0, stream>>>(Bbuf, Cbuf, CBb);
  yd_states_k<<<B_ * NC * HEADS, 512, 0, stream>>>(xb16, Bbuf, dtb, CBb, alog, ydb16, states);
  scan_k<<<B_ * HEADS * P_ * NSTATE / 256, 256, 0, stream>>>(states, dts, alog, prevb);
  yo_final_k<<<B_ * NC * HEADS, 512, 0, stream>>>(xb16, Cbuf, dtb, prevb, alog, Dv, ydb16, ybf);
  ln_gate_k<<<MTOK, 256, 0, stream>>>(ybf, gateb, lnw, lnb, yact);
  gemm_bt_k<0><<<dim3(H_ / 128, MTOK / 128), 256, 0, stream>>>(
      yact, w2b, out, nullptr, nullptr, INTER, H_);
}